// Round 15
// baseline (823.529 us; speedup 1.0000x reference)
//
#include <hip/hip_runtime.h>
#include <math.h>

#define Nn     512
#define Ll     500
#define TSTEPS 800
#define TPH    400    // phases; 2 sim-steps per phase
#define NWG    64
#define NJ     8      // nodes per workgroup
#define NT     576    // 9 waves: wave0 control, waves 1-8 gather
#define NEEG   64
#define NB_    40
#define NH_    20
#define KBUF   8      // step-indexed ring (power of 2)
#define SCALE_    524288.0f
#define INVSCALE_ (1.0f/524288.0f)

// d_ws layout (float/u32 indices)
#define OFF_SUMSQ  0
#define OFF_ABORT  1
#define OFF_ROWSUM 64                     // f32[512]
#define OFF_EEG    576                    // f32[2560]
#define OFF_ZEND   3200                   // zero [0, OFF_ZEND)
#define OFF_TBUF   3200                   // u32[KBUF*Nn*NWG]
#define TBUF_WORDS (KBUF*Nn*NWG)

__device__ __forceinline__ float relu_(float x) { return fmaxf(x, 0.0f); }
__device__ __forceinline__ int sext25_(unsigned u) { return ((int)(u << 7)) >> 7; }

__global__ void k_ws(const float* __restrict__ wbb, const float* __restrict__ sc,
                     float* __restrict__ ws)
{
    int i = blockIdx.x, tid = threadIdx.x;
    float rs = 0.f, sq = 0.f;
    for (int j = tid; j < Nn; j += 256) {
        float wij = expf(wbb[i*Nn+j]) * sc[i*Nn+j];
        float wji = expf(wbb[j*Nn+i]) * sc[j*Nn+i];
        float v = log1pf(0.5f*(wij + wji));
        rs += v; sq += v*v;
    }
    #pragma unroll
    for (int off = 32; off > 0; off >>= 1) { rs += __shfl_down(rs, off); sq += __shfl_down(sq, off); }
    __shared__ float srs[4], ssq[4];
    int wv = tid >> 6, ln = tid & 63;
    if (ln == 0) { srs[wv] = rs; ssq[wv] = sq; }
    __syncthreads();
    if (tid == 0) {
        ws[OFF_ROWSUM + i] = srs[0]+srs[1]+srs[2]+srs[3];
        atomicAdd(&ws[OFF_SUMSQ], ssq[0]+ssq[1]+ssq[2]+ssq[3]);
    }
}

__global__ __launch_bounds__(NT) void k_main(
    const float* __restrict__ input, const float* __restrict__ noise_in,
    const float* __restrict__ hx, const float* __restrict__ hE,
    const float* __restrict__ dist, const float* __restrict__ W_in,
    const float* __restrict__ theta, const float* __restrict__ wbb,
    const float* __restrict__ sc, const float* __restrict__ lm,
    float* __restrict__ ws)
{
    __shared__ float hist[NJ][512];          // 16 KB
    __shared__ float wn[NJ][Nn];             // 16 KB
    __shared__ unsigned short dd[NJ][Nn];    //  8 KB (delays clamped to >=2)
    __shared__ float u_l[TSTEPS*2];          // 6.4 KB
    __shared__ float noise_l[NJ][TSTEPS];    // 25.6 KB
    __shared__ float lmt_l[NEEG][NJ];        //  2 KB
    __shared__ float eeg_l[NB_][NEEG];       // 10.2 KB
    __shared__ float colmean[NJ];
    __shared__ float eim[NJ];
    __shared__ unsigned abort_s;

    const int w   = blockIdx.x;
    const int tid = threadIdx.x;
    const int j0  = w*NJ;
    float* histf  = &hist[0][0];
    const float dt = 0.05f;

    float th[16];
    #pragma unroll
    for (int k = 0; k < 16; ++k) th[k] = theta[k];
    const float kg   = 0.01f + relu_(th[0]);
    const float kc1  = 0.01f + relu_(th[1]);
    const float kc2  = 0.01f + relu_(th[2]);
    const float kc3  = 0.01f + relu_(th[3]);
    const float kc4  = 0.01f + relu_(th[4]);
    const float kstd = 150.0f + relu_(th[5]);
    const float rA   = relu_(th[6]);
    const float aa   = 1.0f + relu_(th[7]);
    const float rB   = relu_(th[8]);
    const float ab   = 1.0f + relu_(th[9]);
    const float vmax = th[10], v0p = th[11], rr = th[12];
    const float den  = 1.5f + relu_(th[15]);
    const float invnorm = 1.0f / sqrtf(ws[OFF_SUMSQ]);

    if (tid == 0) abort_s = 0u;

    for (int idx = tid; idx < NJ*Nn; idx += NT) {
        int jl = idx >> 9, i = idx & 511;
        int jg = j0 + jl;
        float wij = expf(wbb[jg*Nn+i]) * sc[jg*Nn+i];
        float wji = expf(wbb[i*Nn+jg]) * sc[i*Nn+jg];
        wn[jl][i] = log1pf(0.5f*(wij + wji)) * invnorm;
        int d = (int)(dist[jg*Nn + i] / den);
        dd[jl][i] = (unsigned short)(d < 2 ? 2 : d);
    }
    for (int idx = tid; idx < NJ*512; idx += NT) {
        int jl = idx >> 9, s = idx & 511;
        int k = 511 - s;
        hist[jl][s] = (k < Ll) ? hE[(j0+jl)*Ll + k] : 0.0f;
    }
    for (int idx = tid; idx < TSTEPS*2; idx += NT) {
        int t = idx >> 1, s = idx & 1;
        int tt = (t % NH_)*NB_ + (t / NH_);
        u_l[idx] = input[tt*2 + s];
    }
    for (int idx = tid; idx < NJ*TSTEPS; idx += NT) {
        int jl = idx / TSTEPS, t = idx % TSTEPS;
        int tt = (t % NH_)*NB_ + (t / NH_);
        noise_l[jl][t] = noise_in[(size_t)(j0+jl)*(NH_*NB_*3) + tt*3];
    }
    if (tid < NJ) {
        float s = 0.f;
        for (int e = 0; e < NEEG; ++e) s += lm[e*Nn + j0 + tid];
        colmean[tid] = s * (1.0f/NEEG);
    }
    __syncthreads();
    for (int idx = tid; idx < NEEG*NJ; idx += NT) {
        int e = idx / NJ, jl = idx - e*NJ;
        lmt_l[e][jl] = lm[e*Nn + j0 + jl] - colmean[jl];
    }
    float stM=0,stE=0,stI=0,stMv=0,stEv=0,stIv=0, dgd_r=0, win0=0, win1=0;
    if (tid < NJ) {
        stM  = hx[(j0+tid)*6+0]; stE  = hx[(j0+tid)*6+1]; stI  = hx[(j0+tid)*6+2];
        stMv = hx[(j0+tid)*6+3]; stEv = hx[(j0+tid)*6+4]; stIv = hx[(j0+tid)*6+5];
        dgd_r = -ws[OFF_ROWSUM + j0 + tid] * invnorm;
        win0 = W_in[(j0+tid)*2+0]; win1 = W_in[(j0+tid)*2+1];
    }
    __syncthreads();

    unsigned* abortf = (unsigned*)ws + OFF_ABORT;
    unsigned* tbuf   = (unsigned*)ws + OFF_TBUF;

    // prologue: seed steps 0,1 (slots 0,1 / tags 0,1); set phase-0 gather offsets
    float wnr[NJ];
    int   ofsA[NJ];
    if (tid >= 64) {
        const int gt = tid - 64;
        float pa = 0.f, pb = 0.f;
        #pragma unroll
        for (int jl = 0; jl < NJ; ++jl) {
            int d = (int)dd[jl][gt];
            wnr[jl] = wn[jl][gt];
            ofsA[jl] = (1 - d) & 511;                // phase q reads (2q+1-d) and +1
            pa += wnr[jl] * hist[jl][(511 - d) & 511];   // step 0: E(-1-d)
            pb += wnr[jl] * hist[jl][(512 - d) & 511];   // step 1: E(-d)
        }
        __hip_atomic_store(&tbuf[0*(Nn*NWG) + w*512 + gt],
                           (unsigned)(int)lrintf(pa*SCALE_) & 0x1FFFFFFu,
                           __ATOMIC_RELAXED, __HIP_MEMORY_SCOPE_AGENT);
        __hip_atomic_store(&tbuf[1*(Nn*NWG) + w*512 + gt],
                           (1u<<25) | ((unsigned)(int)lrintf(pb*SCALE_) & 0x1FFFFFFu),
                           __ATOMIC_RELAXED, __HIP_MEMORY_SCOPE_AGENT);
    }
    asm volatile("s_waitcnt vmcnt(0)" ::: "memory");
    __syncthreads();

    // consumer preload: steps 0 (set A) and 1 (set B)
    unsigned xA0=0,xA1=0,xA2=0,xA3=0,xA4=0,xA5=0,xA6=0,xA7=0;
    unsigned xB0=0,xB1=0,xB2=0,xB3=0,xB4=0,xB5=0,xB6=0,xB7=0;
    int pg8 = 0;
    const unsigned* pj = nullptr;
    if (tid < 64) {
        pg8 = (tid >> 3) * 8;
        pj  = tbuf + j0 + (tid & 7);
        const unsigned* p0 = pj;
        xA0 = __hip_atomic_load(&p0[(pg8+0)*512], __ATOMIC_RELAXED, __HIP_MEMORY_SCOPE_AGENT);
        xA1 = __hip_atomic_load(&p0[(pg8+1)*512], __ATOMIC_RELAXED, __HIP_MEMORY_SCOPE_AGENT);
        xA2 = __hip_atomic_load(&p0[(pg8+2)*512], __ATOMIC_RELAXED, __HIP_MEMORY_SCOPE_AGENT);
        xA3 = __hip_atomic_load(&p0[(pg8+3)*512], __ATOMIC_RELAXED, __HIP_MEMORY_SCOPE_AGENT);
        xA4 = __hip_atomic_load(&p0[(pg8+4)*512], __ATOMIC_RELAXED, __HIP_MEMORY_SCOPE_AGENT);
        xA5 = __hip_atomic_load(&p0[(pg8+5)*512], __ATOMIC_RELAXED, __HIP_MEMORY_SCOPE_AGENT);
        xA6 = __hip_atomic_load(&p0[(pg8+6)*512], __ATOMIC_RELAXED, __HIP_MEMORY_SCOPE_AGENT);
        xA7 = __hip_atomic_load(&p0[(pg8+7)*512], __ATOMIC_RELAXED, __HIP_MEMORY_SCOPE_AGENT);
        const unsigned* p1 = pj + 1*(Nn*NWG);
        xB0 = __hip_atomic_load(&p1[(pg8+0)*512], __ATOMIC_RELAXED, __HIP_MEMORY_SCOPE_AGENT);
        xB1 = __hip_atomic_load(&p1[(pg8+1)*512], __ATOMIC_RELAXED, __HIP_MEMORY_SCOPE_AGENT);
        xB2 = __hip_atomic_load(&p1[(pg8+2)*512], __ATOMIC_RELAXED, __HIP_MEMORY_SCOPE_AGENT);
        xB3 = __hip_atomic_load(&p1[(pg8+3)*512], __ATOMIC_RELAXED, __HIP_MEMORY_SCOPE_AGENT);
        xB4 = __hip_atomic_load(&p1[(pg8+4)*512], __ATOMIC_RELAXED, __HIP_MEMORY_SCOPE_AGENT);
        xB5 = __hip_atomic_load(&p1[(pg8+5)*512], __ATOMIC_RELAXED, __HIP_MEMORY_SCOPE_AGENT);
        xB6 = __hip_atomic_load(&p1[(pg8+6)*512], __ATOMIC_RELAXED, __HIP_MEMORY_SCOPE_AGENT);
        xB7 = __hip_atomic_load(&p1[(pg8+7)*512], __ATOMIC_RELAXED, __HIP_MEMORY_SCOPE_AGENT);
    }

    for (int q = 0; q < TPH; ++q) {
        const int tA = 2*q, tB = 2*q + 1;
        // ---- pre-phase: step-A positions (coupling-independent) ----
        float MpA=0.f, EpA=0.f, IpA=0.f;
        if (tid < NJ) {
            MpA = stM + dt*stMv;
            EpA = stE + dt*stEv;
            IpA = stI + dt*stIv;
            hist[tid][tA & 511] = EpA;
        }
        asm volatile("s_waitcnt lgkmcnt(0)" ::: "memory");
        __builtin_amdgcn_s_barrier();
        __builtin_amdgcn_sched_barrier(0);
        if (abort_s) break;

        if (tid >= 64) {
            // gather: publish steps {2q+2, 2q+3} (consumed next phase)
            if (q < TPH-1) {
                const int gt = tid - 64;
                float gA = 0.f, gB = 0.f;
                #pragma unroll
                for (int jl = 0; jl < NJ; ++jl) {
                    int o = ofsA[jl];
                    gA += wnr[jl] * histf[jl*512 + o];
                    gB += wnr[jl] * histf[jl*512 + ((o+1) & 511)];
                    ofsA[jl] = (o + 2) & 511;
                }
                unsigned* bA = tbuf + ((tA+2) & (KBUF-1))*(Nn*NWG);
                unsigned* bB = tbuf + ((tB+2) & (KBUF-1))*(Nn*NWG);
                __hip_atomic_store(&bA[w*512 + gt],
                                   ((unsigned)((tA+2) & 127) << 25) |
                                   ((unsigned)(int)lrintf(gA*SCALE_) & 0x1FFFFFFu),
                                   __ATOMIC_RELAXED, __HIP_MEMORY_SCOPE_AGENT);
                __hip_atomic_store(&bB[w*512 + gt],
                                   ((unsigned)((tB+2) & 127) << 25) |
                                   ((unsigned)(int)lrintf(gB*SCALE_) & 0x1FFFFFFu),
                                   __ATOMIC_RELAXED, __HIP_MEMORY_SCOPE_AGENT);
            }
            // EEG dot for the boundary that ended LAST phase (eim written mid-phase q-1)
            if ((q % 10) == 0 && q > 0 && tid < 64 + NEEG) {
                int e = tid - 64;
                float s = 0.f;
                #pragma unroll
                for (int jl = 0; jl < NJ; ++jl) s += lmt_l[e][jl]*eim[jl];
                eeg_l[q/10 - 1][e] = s;
            }
        } else {
            // ---- control: step A sigmoids (entering state) ----
            float stimA=0.f, rE0A=0.f, nMvA=0.f, nIvA=0.f, nzA=0.f, nzB=0.f;
            if (tid < NJ) {
                nzA = noise_l[tid][tA];
                nzB = noise_l[tid][tB];
                stimA = win0*u_l[2*tA] + win1*u_l[2*tA+1];
                float rM  = vmax / (1.0f + expf(-rr*((stE - stI) - v0p)));
                float s1v = vmax / (1.0f + expf(-rr*((kc1*stM)  - v0p)));
                float s3v = vmax / (1.0f + expf(-rr*((kc3*stM)  - v0p)));
                float rI  = kc4*s3v;
                rE0A = kg*(dgd_r*stE) + kc2*s1v;
                nMvA = stMv + dt*(rA*aa*(500.0f*tanhf(rM*0.002f)) - 2.0f*aa*stMv - aa*aa*stM);
                nIvA = stIv + dt*(rB*ab*(500.0f*tanhf(rI*0.002f)) - 2.0f*ab*stIv - ab*ab*stI);
            }
            const unsigned tgA = (unsigned)(tA & 127), tgB = (unsigned)(tB & 127);
            bool okA = ((xA0>>25)==tgA)&&((xA1>>25)==tgA)&&((xA2>>25)==tgA)&&((xA3>>25)==tgA)
                    && ((xA4>>25)==tgA)&&((xA5>>25)==tgA)&&((xA6>>25)==tgA)&&((xA7>>25)==tgA);
            bool okB = ((xB0>>25)==tgB)&&((xB1>>25)==tgB)&&((xB2>>25)==tgB)&&((xB3>>25)==tgB)
                    && ((xB4>>25)==tgB)&&((xB5>>25)==tgB)&&((xB6>>25)==tgB)&&((xB7>>25)==tgB);
            unsigned spins = 0; bool to = false;
            const unsigned* pA_ = pj + (tA & (KBUF-1))*(Nn*NWG);
            const unsigned* pB_ = pj + (tB & (KBUF-1))*(Nn*NWG);
            while (!__all(okA && okB)) {
                if (!okA) {
                    xA0 = __hip_atomic_load(&pA_[(pg8+0)*512], __ATOMIC_RELAXED, __HIP_MEMORY_SCOPE_AGENT);
                    xA1 = __hip_atomic_load(&pA_[(pg8+1)*512], __ATOMIC_RELAXED, __HIP_MEMORY_SCOPE_AGENT);
                    xA2 = __hip_atomic_load(&pA_[(pg8+2)*512], __ATOMIC_RELAXED, __HIP_MEMORY_SCOPE_AGENT);
                    xA3 = __hip_atomic_load(&pA_[(pg8+3)*512], __ATOMIC_RELAXED, __HIP_MEMORY_SCOPE_AGENT);
                    xA4 = __hip_atomic_load(&pA_[(pg8+4)*512], __ATOMIC_RELAXED, __HIP_MEMORY_SCOPE_AGENT);
                    xA5 = __hip_atomic_load(&pA_[(pg8+5)*512], __ATOMIC_RELAXED, __HIP_MEMORY_SCOPE_AGENT);
                    xA6 = __hip_atomic_load(&pA_[(pg8+6)*512], __ATOMIC_RELAXED, __HIP_MEMORY_SCOPE_AGENT);
                    xA7 = __hip_atomic_load(&pA_[(pg8+7)*512], __ATOMIC_RELAXED, __HIP_MEMORY_SCOPE_AGENT);
                    okA = ((xA0>>25)==tgA)&&((xA1>>25)==tgA)&&((xA2>>25)==tgA)&&((xA3>>25)==tgA)
                       && ((xA4>>25)==tgA)&&((xA5>>25)==tgA)&&((xA6>>25)==tgA)&&((xA7>>25)==tgA);
                }
                if (!okB) {
                    xB0 = __hip_atomic_load(&pB_[(pg8+0)*512], __ATOMIC_RELAXED, __HIP_MEMORY_SCOPE_AGENT);
                    xB1 = __hip_atomic_load(&pB_[(pg8+1)*512], __ATOMIC_RELAXED, __HIP_MEMORY_SCOPE_AGENT);
                    xB2 = __hip_atomic_load(&pB_[(pg8+2)*512], __ATOMIC_RELAXED, __HIP_MEMORY_SCOPE_AGENT);
                    xB3 = __hip_atomic_load(&pB_[(pg8+3)*512], __ATOMIC_RELAXED, __HIP_MEMORY_SCOPE_AGENT);
                    xB4 = __hip_atomic_load(&pB_[(pg8+4)*512], __ATOMIC_RELAXED, __HIP_MEMORY_SCOPE_AGENT);
                    xB5 = __hip_atomic_load(&pB_[(pg8+5)*512], __ATOMIC_RELAXED, __HIP_MEMORY_SCOPE_AGENT);
                    xB6 = __hip_atomic_load(&pB_[(pg8+6)*512], __ATOMIC_RELAXED, __HIP_MEMORY_SCOPE_AGENT);
                    xB7 = __hip_atomic_load(&pB_[(pg8+7)*512], __ATOMIC_RELAXED, __HIP_MEMORY_SCOPE_AGENT);
                    okB = ((xB0>>25)==tgB)&&((xB1>>25)==tgB)&&((xB2>>25)==tgB)&&((xB3>>25)==tgB)
                       && ((xB4>>25)==tgB)&&((xB5>>25)==tgB)&&((xB6>>25)==tgB)&&((xB7>>25)==tgB);
                }
                if ((++spins & 255u) == 0u) {
                    if (__hip_atomic_load(abortf, __ATOMIC_RELAXED, __HIP_MEMORY_SCOPE_AGENT) != 0u ||
                        spins > (1u<<18)) {
                        __hip_atomic_store(abortf, 1u, __ATOMIC_RELAXED, __HIP_MEMORY_SCOPE_AGENT);
                        to = true; break;
                    }
                }
            }
            if (to) {
                if (tid == 0) abort_s = 1u;
            } else {
                int qsA = sext25_(xA0)+sext25_(xA1)+sext25_(xA2)+sext25_(xA3)
                        + sext25_(xA4)+sext25_(xA5)+sext25_(xA6)+sext25_(xA7);
                int qsB = sext25_(xB0)+sext25_(xB1)+sext25_(xB2)+sext25_(xB3)
                        + sext25_(xB4)+sext25_(xB5)+sext25_(xB6)+sext25_(xB7);
                qsA += __shfl_xor(qsA, 8);  qsB += __shfl_xor(qsB, 8);
                qsA += __shfl_xor(qsA, 16); qsB += __shfl_xor(qsB, 16);
                qsA += __shfl_xor(qsA, 32); qsB += __shfl_xor(qsB, 32);
                // refill both sets for next phase (steps 2q+2, 2q+3)
                if (q < TPH-1) {
                    const unsigned* nA = pj + ((tA+2) & (KBUF-1))*(Nn*NWG);
                    const unsigned* nB = pj + ((tB+2) & (KBUF-1))*(Nn*NWG);
                    xA0 = __hip_atomic_load(&nA[(pg8+0)*512], __ATOMIC_RELAXED, __HIP_MEMORY_SCOPE_AGENT);
                    xA1 = __hip_atomic_load(&nA[(pg8+1)*512], __ATOMIC_RELAXED, __HIP_MEMORY_SCOPE_AGENT);
                    xA2 = __hip_atomic_load(&nA[(pg8+2)*512], __ATOMIC_RELAXED, __HIP_MEMORY_SCOPE_AGENT);
                    xA3 = __hip_atomic_load(&nA[(pg8+3)*512], __ATOMIC_RELAXED, __HIP_MEMORY_SCOPE_AGENT);
                    xA4 = __hip_atomic_load(&nA[(pg8+4)*512], __ATOMIC_RELAXED, __HIP_MEMORY_SCOPE_AGENT);
                    xA5 = __hip_atomic_load(&nA[(pg8+5)*512], __ATOMIC_RELAXED, __HIP_MEMORY_SCOPE_AGENT);
                    xA6 = __hip_atomic_load(&nA[(pg8+6)*512], __ATOMIC_RELAXED, __HIP_MEMORY_SCOPE_AGENT);
                    xA7 = __hip_atomic_load(&nA[(pg8+7)*512], __ATOMIC_RELAXED, __HIP_MEMORY_SCOPE_AGENT);
                    xB0 = __hip_atomic_load(&nB[(pg8+0)*512], __ATOMIC_RELAXED, __HIP_MEMORY_SCOPE_AGENT);
                    xB1 = __hip_atomic_load(&nB[(pg8+1)*512], __ATOMIC_RELAXED, __HIP_MEMORY_SCOPE_AGENT);
                    xB2 = __hip_atomic_load(&nB[(pg8+2)*512], __ATOMIC_RELAXED, __HIP_MEMORY_SCOPE_AGENT);
                    xB3 = __hip_atomic_load(&nB[(pg8+3)*512], __ATOMIC_RELAXED, __HIP_MEMORY_SCOPE_AGENT);
                    xB4 = __hip_atomic_load(&nB[(pg8+4)*512], __ATOMIC_RELAXED, __HIP_MEMORY_SCOPE_AGENT);
                    xB5 = __hip_atomic_load(&nB[(pg8+5)*512], __ATOMIC_RELAXED, __HIP_MEMORY_SCOPE_AGENT);
                    xB6 = __hip_atomic_load(&nB[(pg8+6)*512], __ATOMIC_RELAXED, __HIP_MEMORY_SCOPE_AGENT);
                    xB7 = __hip_atomic_load(&nB[(pg8+7)*512], __ATOMIC_RELAXED, __HIP_MEMORY_SCOPE_AGENT);
                }
                if (tid < NJ) {
                    // ---- finish step A ----
                    float LEdA = (float)qsA * INVSCALE_;
                    float rEA  = rE0A + kstd*nzA + kg*LEdA;
                    float EvA  = stEv + dt*(rA*aa*(stimA + 500.0f*tanhf(rEA*0.002f)) - 2.0f*aa*stEv - aa*aa*stE);
                    // ---- step B positions ----
                    float MpB = MpA + dt*nMvA;
                    float EpB = EpA + dt*EvA;
                    float IpB = IpA + dt*nIvA;
                    hist[tid][tB & 511] = EpB;
                    // ---- step B sigmoids (positions after A) + velocities ----
                    float rMB  = vmax / (1.0f + expf(-rr*((EpA - IpA) - v0p)));
                    float s1vB = vmax / (1.0f + expf(-rr*((kc1*MpA) - v0p)));
                    float s3vB = vmax / (1.0f + expf(-rr*((kc3*MpA) - v0p)));
                    float rIB  = kc4*s3vB;
                    float stimB = win0*u_l[2*tB] + win1*u_l[2*tB+1];
                    float rEB = kg*(dgd_r*EpA) + kc2*s1vB + kstd*nzB + kg*((float)qsB * INVSCALE_);
                    float MvB = nMvA + dt*(rA*aa*(500.0f*tanhf(rMB*0.002f)) - 2.0f*aa*nMvA - aa*aa*MpA);
                    float EvB = EvA  + dt*(rA*aa*(stimB + 500.0f*tanhf(rEB*0.002f)) - 2.0f*aa*EvA - aa*aa*EpA);
                    float IvB = nIvA + dt*(rB*ab*(500.0f*tanhf(rIB*0.002f)) - 2.0f*ab*nIvA - ab*ab*IpA);
                    if ((q % 10) == 9) eim[tid] = EpB - IpB;   // boundary is always step B
                    // commit (state entering next phase)
                    stM = MpB; stE = EpB; stI = IpB;
                    stMv = MvB; stEv = EvB; stIv = IvB;
                }
            }
        }
    }

    // final EEG boundary (q=399, tbc=39) — eim written mid-last-phase
    __syncthreads();
    if (abort_s == 0u) {
        if (tid < NEEG) {
            float s = 0.f;
            #pragma unroll
            for (int jl = 0; jl < NJ; ++jl) s += lmt_l[tid][jl]*eim[jl];
            eeg_l[NB_-1][tid] = s;
        }
        __syncthreads();
        const float* el = &eeg_l[0][0];
        for (int idx = tid; idx < NB_*NEEG; idx += NT)
            atomicAdd(&ws[OFF_EEG + idx], el[idx]);
    }
}

__global__ void k_out(const float* __restrict__ ws, const float* __restrict__ theta,
                      float* __restrict__ out)
{
    int idx = blockIdx.x*256 + threadIdx.x;
    if (idx < NB_*NEEG) out[idx] = 0.01f*theta[13]*ws[OFF_EEG + idx] - theta[14];
}

extern "C" void kernel_launch(void* const* d_in, const int* in_sizes, int n_in,
                              void* d_out, int out_size, void* d_ws, size_t ws_size,
                              hipStream_t stream)
{
    const float* input    = (const float*)d_in[0];
    const float* noise_in = (const float*)d_in[1];
    const float* hx       = (const float*)d_in[3];
    const float* hE       = (const float*)d_in[4];
    const float* sc       = (const float*)d_in[5];
    const float* dist     = (const float*)d_in[6];
    const float* w_bb     = (const float*)d_in[7];
    const float* W_in     = (const float*)d_in[8];
    const float* lm       = (const float*)d_in[10];
    const float* theta    = (const float*)d_in[11];
    float* ws  = (float*)d_ws;
    float* out = (float*)d_out;

    hipMemsetAsync(d_ws, 0, (size_t)OFF_ZEND*4, stream);
    hipMemsetAsync((char*)d_ws + (size_t)OFF_TBUF*4, 0xFF,
                   (size_t)TBUF_WORDS*4, stream);              // tags invalid
    k_ws  <<<Nn, 256, 0, stream>>>(w_bb, sc, ws);
    k_main<<<NWG, NT, 0, stream>>>(input, noise_in, hx, hE, dist, W_in, theta,
                                   w_bb, sc, lm, ws);
    k_out <<<(NB_*NEEG + 255)/256, 256, 0, stream>>>(ws, theta, out);
}

// Round 16
// 822.084 us; speedup vs baseline: 1.0018x; 1.0018x over previous
//
#include <hip/hip_runtime.h>
#include <math.h>

#define Nn     512
#define Ll     500
#define TSTEPS 800
#define NWG    64
#define NJ     8      // nodes per workgroup
#define NT     576    // 9 waves: wave0 control, waves 1-8 gather
#define NEEG   64
#define NB_    40
#define NH_    20
#define KBUF   8      // step-indexed ring (power of 2)
#define SCALE_    524288.0f
#define INVSCALE_ (1.0f/524288.0f)

// d_ws layout (float/u32 indices)
#define OFF_SUMSQ  0
#define OFF_ABORT  1
#define OFF_ROWSUM 64                     // f32[512]
#define OFF_EEG    576                    // f32[2560]
#define OFF_ZEND   3200                   // zero [0, OFF_ZEND)
#define OFF_TBUF   3200                   // u32[KBUF*Nn*NWG]
#define TBUF_WORDS (KBUF*Nn*NWG)

__device__ __forceinline__ float relu_(float x) { return fmaxf(x, 0.0f); }
__device__ __forceinline__ int sext25_(unsigned u) { return ((int)(u << 7)) >> 7; }

__global__ void k_ws(const float* __restrict__ wbb, const float* __restrict__ sc,
                     float* __restrict__ ws)
{
    int i = blockIdx.x, tid = threadIdx.x;
    float rs = 0.f, sq = 0.f;
    for (int j = tid; j < Nn; j += 256) {
        float wij = expf(wbb[i*Nn+j]) * sc[i*Nn+j];
        float wji = expf(wbb[j*Nn+i]) * sc[j*Nn+i];
        float v = log1pf(0.5f*(wij + wji));
        rs += v; sq += v*v;
    }
    #pragma unroll
    for (int off = 32; off > 0; off >>= 1) { rs += __shfl_down(rs, off); sq += __shfl_down(sq, off); }
    __shared__ float srs[4], ssq[4];
    int wv = tid >> 6, ln = tid & 63;
    if (ln == 0) { srs[wv] = rs; ssq[wv] = sq; }
    __syncthreads();
    if (tid == 0) {
        ws[OFF_ROWSUM + i] = srs[0]+srs[1]+srs[2]+srs[3];
        atomicAdd(&ws[OFF_SUMSQ], ssq[0]+ssq[1]+ssq[2]+ssq[3]);
    }
}

__global__ __launch_bounds__(NT) void k_main(
    const float* __restrict__ input, const float* __restrict__ noise_in,
    const float* __restrict__ hx, const float* __restrict__ hE,
    const float* __restrict__ dist, const float* __restrict__ W_in,
    const float* __restrict__ theta, const float* __restrict__ wbb,
    const float* __restrict__ sc, const float* __restrict__ lm,
    float* __restrict__ ws)
{
    __shared__ float hist[NJ][512];          // 16 KB
    __shared__ float wn[NJ][Nn];             // 16 KB
    __shared__ unsigned short dd[NJ][Nn];    //  8 KB (delays clamped to >=3)
    __shared__ float u_l[TSTEPS*2];          // 6.4 KB
    __shared__ float noise_l[NJ][TSTEPS];    // 25.6 KB
    __shared__ float lmt_l[NEEG][NJ];        //  2 KB
    __shared__ float eeg_l[NB_][NEEG];       // 10.2 KB
    __shared__ float colmean[NJ];
    __shared__ float eim[NJ];
    __shared__ unsigned abort_s;

    const int w   = blockIdx.x;
    const int tid = threadIdx.x;
    const int j0  = w*NJ;
    float* histf  = &hist[0][0];

    float th[16];
    #pragma unroll
    for (int k = 0; k < 16; ++k) th[k] = theta[k];
    const float kg   = 0.01f + relu_(th[0]);
    const float kc1  = 0.01f + relu_(th[1]);
    const float kc2  = 0.01f + relu_(th[2]);
    const float kc3  = 0.01f + relu_(th[3]);
    const float kc4  = 0.01f + relu_(th[4]);
    const float kstd = 150.0f + relu_(th[5]);
    const float rA   = relu_(th[6]);
    const float aa   = 1.0f + relu_(th[7]);
    const float rB   = relu_(th[8]);
    const float ab   = 1.0f + relu_(th[9]);
    const float vmax = th[10], v0p = th[11], rr = th[12];
    const float den  = 1.5f + relu_(th[15]);
    const float invnorm = 1.0f / sqrtf(ws[OFF_SUMSQ]);

    if (tid == 0) abort_s = 0u;

    // weights (bitwise == k_ws terms) + delays CLAMPED to >=3 (K=4 publish-ahead)
    for (int idx = tid; idx < NJ*Nn; idx += NT) {
        int jl = idx >> 9, i = idx & 511;
        int jg = j0 + jl;
        float wij = expf(wbb[jg*Nn+i]) * sc[jg*Nn+i];
        float wji = expf(wbb[i*Nn+jg]) * sc[i*Nn+jg];
        wn[jl][i] = log1pf(0.5f*(wij + wji)) * invnorm;
        int d = (int)(dist[jg*Nn + i] / den);
        dd[jl][i] = (unsigned short)(d < 3 ? 3 : d);
    }
    // slot s holds E(tau), s = tau mod 512; initial: tau=-1-k -> hE[:,k]
    for (int idx = tid; idx < NJ*512; idx += NT) {
        int jl = idx >> 9, s = idx & 511;
        int k = 511 - s;
        hist[jl][s] = (k < Ll) ? hE[(j0+jl)*Ll + k] : 0.0f;
    }
    for (int idx = tid; idx < TSTEPS*2; idx += NT) {
        int t = idx >> 1, s = idx & 1;
        int tt = (t % NH_)*NB_ + (t / NH_);
        u_l[idx] = input[tt*2 + s];
    }
    for (int idx = tid; idx < NJ*TSTEPS; idx += NT) {
        int jl = idx / TSTEPS, t = idx % TSTEPS;
        int tt = (t % NH_)*NB_ + (t / NH_);
        noise_l[jl][t] = noise_in[(size_t)(j0+jl)*(NH_*NB_*3) + tt*3];
    }
    if (tid < NJ) {
        float s = 0.f;
        for (int e = 0; e < NEEG; ++e) s += lm[e*Nn + j0 + tid];
        colmean[tid] = s * (1.0f/NEEG);
    }
    __syncthreads();
    for (int idx = tid; idx < NEEG*NJ; idx += NT) {
        int e = idx / NJ, jl = idx - e*NJ;
        lmt_l[e][jl] = lm[e*Nn + j0 + jl] - colmean[jl];
    }
    float stM=0,stE=0,stI=0,stMv=0,stEv=0,stIv=0, dgd_r=0, win0=0, win1=0;
    if (tid < NJ) {
        stM  = hx[(j0+tid)*6+0]; stE  = hx[(j0+tid)*6+1]; stI  = hx[(j0+tid)*6+2];
        stMv = hx[(j0+tid)*6+3]; stEv = hx[(j0+tid)*6+4]; stIv = hx[(j0+tid)*6+5];
        dgd_r = -ws[OFF_ROWSUM + j0 + tid] * invnorm;
        win0 = W_in[(j0+tid)*2+0]; win1 = W_in[(j0+tid)*2+1];
    }
    __syncthreads();

    unsigned* abortf = (unsigned*)ws + OFF_ABORT;
    unsigned* tbuf   = (unsigned*)ws + OFF_TBUF;

    // prologue: seed slots 0..3 (tags 0..3) from initial history (d>=3)
    float wnr[NJ];
    int   ofs[NJ];
    if (tid >= 64) {
        const int gt = tid - 64;
        float p0 = 0.f, p1 = 0.f, p2 = 0.f, p3 = 0.f;
        #pragma unroll
        for (int jl = 0; jl < NJ; ++jl) {
            int d = (int)dd[jl][gt];
            wnr[jl] = wn[jl][gt];
            ofs[jl] = (3 - d) & 511;                 // main(t) reads slot (t+3-d) <= t
            p0 += wnr[jl] * hist[jl][(511 - d) & 511];   // step 0: E(-1-d)
            p1 += wnr[jl] * hist[jl][(512 - d) & 511];   // step 1: E(-d)
            p2 += wnr[jl] * hist[jl][(513 - d) & 511];   // step 2: E(1-d)
            p3 += wnr[jl] * hist[jl][(514 - d) & 511];   // step 3: E(2-d), d>=3
        }
        __hip_atomic_store(&tbuf[0*(Nn*NWG) + w*512 + gt],
                           (unsigned)(int)lrintf(p0*SCALE_) & 0x1FFFFFFu,
                           __ATOMIC_RELAXED, __HIP_MEMORY_SCOPE_AGENT);
        __hip_atomic_store(&tbuf[1*(Nn*NWG) + w*512 + gt],
                           (1u<<25) | ((unsigned)(int)lrintf(p1*SCALE_) & 0x1FFFFFFu),
                           __ATOMIC_RELAXED, __HIP_MEMORY_SCOPE_AGENT);
        __hip_atomic_store(&tbuf[2*(Nn*NWG) + w*512 + gt],
                           (2u<<25) | ((unsigned)(int)lrintf(p2*SCALE_) & 0x1FFFFFFu),
                           __ATOMIC_RELAXED, __HIP_MEMORY_SCOPE_AGENT);
        __hip_atomic_store(&tbuf[3*(Nn*NWG) + w*512 + gt],
                           (3u<<25) | ((unsigned)(int)lrintf(p3*SCALE_) & 0x1FFFFFFu),
                           __ATOMIC_RELAXED, __HIP_MEMORY_SCOPE_AGENT);
    }
    asm volatile("s_waitcnt vmcnt(0)" ::: "memory");
    __syncthreads();

    // consumer: two register sets, each refilled every 2 steps (depth-2 pipeline)
    unsigned a0=0,a1=0,a2=0,a3=0,a4=0,a5=0,a6=0,a7=0;
    unsigned b0=0,b1=0,b2=0,b3=0,b4=0,b5=0,b6=0,b7=0;
    int pg8 = 0;
    const unsigned* pj = nullptr;
    if (tid < 64) {
        pg8 = (tid >> 3) * 8;
        pj  = tbuf + j0 + (tid & 7);
        const unsigned* p0 = pj;                    // slot 0 (step 0)
        a0 = __hip_atomic_load(&p0[(pg8+0)*512], __ATOMIC_RELAXED, __HIP_MEMORY_SCOPE_AGENT);
        a1 = __hip_atomic_load(&p0[(pg8+1)*512], __ATOMIC_RELAXED, __HIP_MEMORY_SCOPE_AGENT);
        a2 = __hip_atomic_load(&p0[(pg8+2)*512], __ATOMIC_RELAXED, __HIP_MEMORY_SCOPE_AGENT);
        a3 = __hip_atomic_load(&p0[(pg8+3)*512], __ATOMIC_RELAXED, __HIP_MEMORY_SCOPE_AGENT);
        a4 = __hip_atomic_load(&p0[(pg8+4)*512], __ATOMIC_RELAXED, __HIP_MEMORY_SCOPE_AGENT);
        a5 = __hip_atomic_load(&p0[(pg8+5)*512], __ATOMIC_RELAXED, __HIP_MEMORY_SCOPE_AGENT);
        a6 = __hip_atomic_load(&p0[(pg8+6)*512], __ATOMIC_RELAXED, __HIP_MEMORY_SCOPE_AGENT);
        a7 = __hip_atomic_load(&p0[(pg8+7)*512], __ATOMIC_RELAXED, __HIP_MEMORY_SCOPE_AGENT);
        const unsigned* p1 = pj + 1*(Nn*NWG);       // slot 1 (step 1)
        b0 = __hip_atomic_load(&p1[(pg8+0)*512], __ATOMIC_RELAXED, __HIP_MEMORY_SCOPE_AGENT);
        b1 = __hip_atomic_load(&p1[(pg8+1)*512], __ATOMIC_RELAXED, __HIP_MEMORY_SCOPE_AGENT);
        b2 = __hip_atomic_load(&p1[(pg8+2)*512], __ATOMIC_RELAXED, __HIP_MEMORY_SCOPE_AGENT);
        b3 = __hip_atomic_load(&p1[(pg8+3)*512], __ATOMIC_RELAXED, __HIP_MEMORY_SCOPE_AGENT);
        b4 = __hip_atomic_load(&p1[(pg8+4)*512], __ATOMIC_RELAXED, __HIP_MEMORY_SCOPE_AGENT);
        b5 = __hip_atomic_load(&p1[(pg8+5)*512], __ATOMIC_RELAXED, __HIP_MEMORY_SCOPE_AGENT);
        b6 = __hip_atomic_load(&p1[(pg8+6)*512], __ATOMIC_RELAXED, __HIP_MEMORY_SCOPE_AGENT);
        b7 = __hip_atomic_load(&p1[(pg8+7)*512], __ATOMIC_RELAXED, __HIP_MEMORY_SCOPE_AGENT);
    }

    int thc = 0, tbc = 0;

    auto stepf = [&](int t,
                     unsigned& x0, unsigned& x1, unsigned& x2, unsigned& x3,
                     unsigned& x4, unsigned& x5, unsigned& x6, unsigned& x7) -> bool
    {
        // ---- pre-phase ----
        float nM_pre=0.f, nE_pre=0.f, nI_pre=0.f;
        if (tid < NJ) {
            nM_pre = stM + 0.05f*stMv;
            nE_pre = stE + 0.05f*stEv;
            nI_pre = stI + 0.05f*stIv;
            hist[tid][t & 511] = nE_pre;
            if (thc == NH_-1) eim[tid] = nE_pre - nI_pre;
        }
        asm volatile("s_waitcnt lgkmcnt(0)" ::: "memory");
        __builtin_amdgcn_s_barrier();
        __builtin_amdgcn_sched_barrier(0);
        if (abort_s) return true;

        // ---- main phase ----
        if (tid >= 64) {
            if (t <= TSTEPS-5) {                       // publish bulk(t+4), K=4
                const int gt = tid - 64;
                float g = 0.f;
                #pragma unroll
                for (int jl = 0; jl < NJ; ++jl) {
                    g += wnr[jl] * histf[jl*512 + ofs[jl]];
                    ofs[jl] = (ofs[jl] + 1) & 511;
                }
                unsigned* bp = tbuf + ((t+4) & (KBUF-1))*(Nn*NWG);
                __hip_atomic_store(&bp[w*512 + gt],
                                   ((unsigned)((t+4) & 127) << 25) |
                                   ((unsigned)(int)lrintf(g*SCALE_) & 0x1FFFFFFu),
                                   __ATOMIC_RELAXED, __HIP_MEMORY_SCOPE_AGENT);
            }
            if (thc == NH_-1 && tid < 64 + NEEG) {
                int e = tid - 64;
                float s = 0.f;
                #pragma unroll
                for (int jl = 0; jl < NJ; ++jl) s += lmt_l[e][jl]*eim[jl];
                eeg_l[tbc][e] = s;
            }
        } else {
            float stim=0.f, rE0=0.f, nMv=0.f, nIv=0.f, nz=0.f;
            if (tid < NJ) {
                nz = noise_l[tid][t];
                stim = win0*u_l[2*t] + win1*u_l[2*t+1];
                float rM  = vmax / (1.0f + expf(-rr*((stE - stI) - v0p)));
                float s1v = vmax / (1.0f + expf(-rr*((kc1*stM)  - v0p)));
                float s3v = vmax / (1.0f + expf(-rr*((kc3*stM)  - v0p)));
                float rI  = kc4*s3v;
                rE0 = kg*(dgd_r*stE) + kc2*s1v;
                nMv = stMv + 0.05f*(rA*aa*(500.0f*tanhf(rM*0.002f)) - 2.0f*aa*stMv - aa*aa*stM);
                nIv = stIv + 0.05f*(rB*ab*(500.0f*tanhf(rI*0.002f)) - 2.0f*ab*stIv - ab*ab*stI);
            }
            const unsigned tg = (unsigned)(t & 127);
            bool ok = ((x0>>25)==tg) && ((x1>>25)==tg) && ((x2>>25)==tg) && ((x3>>25)==tg)
                   && ((x4>>25)==tg) && ((x5>>25)==tg) && ((x6>>25)==tg) && ((x7>>25)==tg);
            unsigned spins = 0; bool to = false;
            const unsigned* pc_ = pj + (t & (KBUF-1))*(Nn*NWG);
            while (!__all(ok)) {
                if (!ok) {
                    x0 = __hip_atomic_load(&pc_[(pg8+0)*512], __ATOMIC_RELAXED, __HIP_MEMORY_SCOPE_AGENT);
                    x1 = __hip_atomic_load(&pc_[(pg8+1)*512], __ATOMIC_RELAXED, __HIP_MEMORY_SCOPE_AGENT);
                    x2 = __hip_atomic_load(&pc_[(pg8+2)*512], __ATOMIC_RELAXED, __HIP_MEMORY_SCOPE_AGENT);
                    x3 = __hip_atomic_load(&pc_[(pg8+3)*512], __ATOMIC_RELAXED, __HIP_MEMORY_SCOPE_AGENT);
                    x4 = __hip_atomic_load(&pc_[(pg8+4)*512], __ATOMIC_RELAXED, __HIP_MEMORY_SCOPE_AGENT);
                    x5 = __hip_atomic_load(&pc_[(pg8+5)*512], __ATOMIC_RELAXED, __HIP_MEMORY_SCOPE_AGENT);
                    x6 = __hip_atomic_load(&pc_[(pg8+6)*512], __ATOMIC_RELAXED, __HIP_MEMORY_SCOPE_AGENT);
                    x7 = __hip_atomic_load(&pc_[(pg8+7)*512], __ATOMIC_RELAXED, __HIP_MEMORY_SCOPE_AGENT);
                    ok = ((x0>>25)==tg) && ((x1>>25)==tg) && ((x2>>25)==tg) && ((x3>>25)==tg)
                      && ((x4>>25)==tg) && ((x5>>25)==tg) && ((x6>>25)==tg) && ((x7>>25)==tg);
                }
                if ((++spins & 255u) == 0u) {
                    if (__hip_atomic_load(abortf, __ATOMIC_RELAXED, __HIP_MEMORY_SCOPE_AGENT) != 0u ||
                        spins > (1u<<18)) {
                        __hip_atomic_store(abortf, 1u, __ATOMIC_RELAXED, __HIP_MEMORY_SCOPE_AGENT);
                        to = true; break;
                    }
                }
            }
            if (to) {
                if (tid == 0) abort_s = 1u;
            } else {
                int qs = sext25_(x0) + sext25_(x1) + sext25_(x2) + sext25_(x3)
                       + sext25_(x4) + sext25_(x5) + sext25_(x6) + sext25_(x7);
                qs += __shfl_xor(qs, 8);
                qs += __shfl_xor(qs, 16);
                qs += __shfl_xor(qs, 32);
                // refill THIS set for step t+2 (published at main(t-2): 2 periods slack)
                if (t + 2 < TSTEPS) {
                    const unsigned* pn = pj + ((t+2) & (KBUF-1))*(Nn*NWG);
                    x0 = __hip_atomic_load(&pn[(pg8+0)*512], __ATOMIC_RELAXED, __HIP_MEMORY_SCOPE_AGENT);
                    x1 = __hip_atomic_load(&pn[(pg8+1)*512], __ATOMIC_RELAXED, __HIP_MEMORY_SCOPE_AGENT);
                    x2 = __hip_atomic_load(&pn[(pg8+2)*512], __ATOMIC_RELAXED, __HIP_MEMORY_SCOPE_AGENT);
                    x3 = __hip_atomic_load(&pn[(pg8+3)*512], __ATOMIC_RELAXED, __HIP_MEMORY_SCOPE_AGENT);
                    x4 = __hip_atomic_load(&pn[(pg8+4)*512], __ATOMIC_RELAXED, __HIP_MEMORY_SCOPE_AGENT);
                    x5 = __hip_atomic_load(&pn[(pg8+5)*512], __ATOMIC_RELAXED, __HIP_MEMORY_SCOPE_AGENT);
                    x6 = __hip_atomic_load(&pn[(pg8+6)*512], __ATOMIC_RELAXED, __HIP_MEMORY_SCOPE_AGENT);
                    x7 = __hip_atomic_load(&pn[(pg8+7)*512], __ATOMIC_RELAXED, __HIP_MEMORY_SCOPE_AGENT);
                }
                if (tid < NJ) {
                    float LEd = (float)qs * INVSCALE_;
                    float rE = rE0 + kstd*nz + kg*LEd;
                    float nEv = stEv + 0.05f*(rA*aa*(stim + 500.0f*tanhf(rE*0.002f)) - 2.0f*aa*stEv - aa*aa*stE);
                    stM = nM_pre; stE = nE_pre; stI = nI_pre;
                    stMv = nMv; stEv = nEv; stIv = nIv;
                }
            }
        }
        return false;
    };

    for (int t = 0; t < TSTEPS; t += 2) {
        if (stepf(t, a0,a1,a2,a3,a4,a5,a6,a7)) break;
        if (thc == NH_-1) { thc = 0; ++tbc; } else ++thc;
        if (stepf(t+1, b0,b1,b2,b3,b4,b5,b6,b7)) break;
        if (thc == NH_-1) { thc = 0; ++tbc; } else ++thc;
    }

    __syncthreads();
    if (abort_s == 0u) {
        const float* el = &eeg_l[0][0];
        for (int idx = tid; idx < NB_*NEEG; idx += NT)
            atomicAdd(&ws[OFF_EEG + idx], el[idx]);
    }
}

__global__ void k_out(const float* __restrict__ ws, const float* __restrict__ theta,
                      float* __restrict__ out)
{
    int idx = blockIdx.x*256 + threadIdx.x;
    if (idx < NB_*NEEG) out[idx] = 0.01f*theta[13]*ws[OFF_EEG + idx] - theta[14];
}

extern "C" void kernel_launch(void* const* d_in, const int* in_sizes, int n_in,
                              void* d_out, int out_size, void* d_ws, size_t ws_size,
                              hipStream_t stream)
{
    const float* input    = (const float*)d_in[0];
    const float* noise_in = (const float*)d_in[1];
    const float* hx       = (const float*)d_in[3];
    const float* hE       = (const float*)d_in[4];
    const float* sc       = (const float*)d_in[5];
    const float* dist     = (const float*)d_in[6];
    const float* w_bb     = (const float*)d_in[7];
    const float* W_in     = (const float*)d_in[8];
    const float* lm       = (const float*)d_in[10];
    const float* theta    = (const float*)d_in[11];
    float* ws  = (float*)d_ws;
    float* out = (float*)d_out;

    hipMemsetAsync(d_ws, 0, (size_t)OFF_ZEND*4, stream);
    hipMemsetAsync((char*)d_ws + (size_t)OFF_TBUF*4, 0xFF,
                   (size_t)TBUF_WORDS*4, stream);              // tags invalid
    k_ws  <<<Nn, 256, 0, stream>>>(w_bb, sc, ws);
    k_main<<<NWG, NT, 0, stream>>>(input, noise_in, hx, hE, dist, W_in, theta,
                                   w_bb, sc, lm, ws);
    k_out <<<(NB_*NEEG + 255)/256, 256, 0, stream>>>(ws, theta, out);
}

// Round 17
// 747.160 us; speedup vs baseline: 1.1022x; 1.1003x over previous
//
#include <hip/hip_runtime.h>
#include <math.h>

#define Nn     512
#define Ll     500
#define TSTEPS 800
#define NWG    64
#define NJ     8      // nodes per workgroup
#define NT     320    // 5 waves: wave0 control, waves 1-4 gather (2 targets/lane)
#define NEEG   64
#define NB_    40
#define NH_    20
#define KBUF   8      // step-indexed ring (power of 2)
#define SCALE_    524288.0f
#define INVSCALE_ (1.0f/524288.0f)

// d_ws layout (float/u32 indices)
#define OFF_SUMSQ  0
#define OFF_ABORT  1
#define OFF_ROWSUM 64                     // f32[512]
#define OFF_EEG    576                    // f32[2560]
#define OFF_ZEND   3200                   // zero [0, OFF_ZEND)
#define OFF_TBUF   3200                   // u32[KBUF*Nn*NWG]
#define TBUF_WORDS (KBUF*Nn*NWG)

__device__ __forceinline__ float relu_(float x) { return fmaxf(x, 0.0f); }
__device__ __forceinline__ int sext25_(unsigned u) { return ((int)(u << 7)) >> 7; }
__device__ __forceinline__ float frcp_(float x) { return __builtin_amdgcn_rcpf(x); }
__device__ __forceinline__ float ftanh_(float x) {          // |err| ~1e-6, x bounded
    float e = __expf(2.0f*x);
    return (e - 1.0f) * frcp_(e + 1.0f);
}

__global__ void k_ws(const float* __restrict__ wbb, const float* __restrict__ sc,
                     float* __restrict__ ws)
{
    int i = blockIdx.x, tid = threadIdx.x;
    float rs = 0.f, sq = 0.f;
    for (int j = tid; j < Nn; j += 256) {
        float wij = expf(wbb[i*Nn+j]) * sc[i*Nn+j];
        float wji = expf(wbb[j*Nn+i]) * sc[j*Nn+i];
        float v = log1pf(0.5f*(wij + wji));
        rs += v; sq += v*v;
    }
    #pragma unroll
    for (int off = 32; off > 0; off >>= 1) { rs += __shfl_down(rs, off); sq += __shfl_down(sq, off); }
    __shared__ float srs[4], ssq[4];
    int wv = tid >> 6, ln = tid & 63;
    if (ln == 0) { srs[wv] = rs; ssq[wv] = sq; }
    __syncthreads();
    if (tid == 0) {
        ws[OFF_ROWSUM + i] = srs[0]+srs[1]+srs[2]+srs[3];
        atomicAdd(&ws[OFF_SUMSQ], ssq[0]+ssq[1]+ssq[2]+ssq[3]);
    }
}

__global__ __launch_bounds__(NT) void k_main(
    const float* __restrict__ input, const float* __restrict__ noise_in,
    const float* __restrict__ hx, const float* __restrict__ hE,
    const float* __restrict__ dist, const float* __restrict__ W_in,
    const float* __restrict__ theta, const float* __restrict__ wbb,
    const float* __restrict__ sc, const float* __restrict__ lm,
    float* __restrict__ ws)
{
    __shared__ float hist[NJ][512];          // 16 KB
    __shared__ float wn[NJ][Nn];             // 16 KB
    __shared__ unsigned short dd[NJ][Nn];    //  8 KB (delays clamped to >=2)
    __shared__ float u_l[TSTEPS*2];          // 6.4 KB
    __shared__ float noise_l[NJ][TSTEPS];    // 25.6 KB
    __shared__ float lmt_l[NEEG][NJ];        //  2 KB
    __shared__ float eeg_l[NB_][NEEG];       // 10.2 KB
    __shared__ float colmean[NJ];
    __shared__ float eim[NJ];
    __shared__ unsigned abort_s;

    const int w   = blockIdx.x;
    const int tid = threadIdx.x;
    const int j0  = w*NJ;
    float* histf  = &hist[0][0];

    float th[16];
    #pragma unroll
    for (int k = 0; k < 16; ++k) th[k] = theta[k];
    const float kg   = 0.01f + relu_(th[0]);
    const float kc1  = 0.01f + relu_(th[1]);
    const float kc2  = 0.01f + relu_(th[2]);
    const float kc3  = 0.01f + relu_(th[3]);
    const float kc4  = 0.01f + relu_(th[4]);
    const float kstd = 150.0f + relu_(th[5]);
    const float rA   = relu_(th[6]);
    const float aa   = 1.0f + relu_(th[7]);
    const float rB   = relu_(th[8]);
    const float ab   = 1.0f + relu_(th[9]);
    const float vmax = th[10], v0p = th[11], rr = th[12];
    const float den  = 1.5f + relu_(th[15]);
    const float invnorm = 1.0f / sqrtf(ws[OFF_SUMSQ]);

    if (tid == 0) abort_s = 0u;

    // weights (bitwise == k_ws terms) + delays CLAMPED to >=2 (K=3 publish-ahead)
    for (int idx = tid; idx < NJ*Nn; idx += NT) {
        int jl = idx >> 9, i = idx & 511;
        int jg = j0 + jl;
        float wij = expf(wbb[jg*Nn+i]) * sc[jg*Nn+i];
        float wji = expf(wbb[i*Nn+jg]) * sc[i*Nn+jg];
        wn[jl][i] = log1pf(0.5f*(wij + wji)) * invnorm;
        int d = (int)(dist[jg*Nn + i] / den);
        dd[jl][i] = (unsigned short)(d < 2 ? 2 : d);
    }
    // slot s holds E(tau), s = tau mod 512; initial: tau=-1-k -> hE[:,k]
    for (int idx = tid; idx < NJ*512; idx += NT) {
        int jl = idx >> 9, s = idx & 511;
        int k = 511 - s;
        hist[jl][s] = (k < Ll) ? hE[(j0+jl)*Ll + k] : 0.0f;
    }
    for (int idx = tid; idx < TSTEPS*2; idx += NT) {
        int t = idx >> 1, s = idx & 1;
        int tt = (t % NH_)*NB_ + (t / NH_);
        u_l[idx] = input[tt*2 + s];
    }
    for (int idx = tid; idx < NJ*TSTEPS; idx += NT) {
        int jl = idx / TSTEPS, t = idx % TSTEPS;
        int tt = (t % NH_)*NB_ + (t / NH_);
        noise_l[jl][t] = noise_in[(size_t)(j0+jl)*(NH_*NB_*3) + tt*3];
    }
    if (tid < NJ) {
        float s = 0.f;
        for (int e = 0; e < NEEG; ++e) s += lm[e*Nn + j0 + tid];
        colmean[tid] = s * (1.0f/NEEG);
    }
    __syncthreads();
    for (int idx = tid; idx < NEEG*NJ; idx += NT) {
        int e = idx / NJ, jl = idx - e*NJ;
        lmt_l[e][jl] = lm[e*Nn + j0 + jl] - colmean[jl];
    }
    float stM=0,stE=0,stI=0,stMv=0,stEv=0,stIv=0, dgd_r=0, win0=0, win1=0;
    if (tid < NJ) {
        stM  = hx[(j0+tid)*6+0]; stE  = hx[(j0+tid)*6+1]; stI  = hx[(j0+tid)*6+2];
        stMv = hx[(j0+tid)*6+3]; stEv = hx[(j0+tid)*6+4]; stIv = hx[(j0+tid)*6+5];
        dgd_r = -ws[OFF_ROWSUM + j0 + tid] * invnorm;
        win0 = W_in[(j0+tid)*2+0]; win1 = W_in[(j0+tid)*2+1];
    }
    __syncthreads();

    unsigned* abortf = (unsigned*)ws + OFF_ABORT;
    unsigned* tbuf   = (unsigned*)ws + OFF_TBUF;

    // prologue: seed slots 0,1,2 (tags 0,1,2) from initial history (d>=2)
    float wnr0[NJ], wnr1[NJ];
    int   ofs0[NJ], ofs1[NJ];
    if (tid >= 64) {
        const int gt = tid - 64;                     // 0..255; targets gt and gt+256
        float pa0=0.f, pb0=0.f, pc0=0.f, pa1=0.f, pb1=0.f, pc1=0.f;
        #pragma unroll
        for (int jl = 0; jl < NJ; ++jl) {
            int d0 = (int)dd[jl][gt], d1 = (int)dd[jl][gt+256];
            wnr0[jl] = wn[jl][gt];  wnr1[jl] = wn[jl][gt+256];
            ofs0[jl] = (2 - d0) & 511;               // main(t) reads slot (t+2-d)
            ofs1[jl] = (2 - d1) & 511;
            pa0 += wnr0[jl] * hist[jl][(511 - d0) & 511];
            pb0 += wnr0[jl] * hist[jl][(512 - d0) & 511];
            pc0 += wnr0[jl] * hist[jl][(513 - d0) & 511];
            pa1 += wnr1[jl] * hist[jl][(511 - d1) & 511];
            pb1 += wnr1[jl] * hist[jl][(512 - d1) & 511];
            pc1 += wnr1[jl] * hist[jl][(513 - d1) & 511];
        }
        const int w0 = w*512 + gt, w1 = w*512 + gt + 256;
        __hip_atomic_store(&tbuf[0*(Nn*NWG) + w0], (unsigned)(int)lrintf(pa0*SCALE_) & 0x1FFFFFFu, __ATOMIC_RELAXED, __HIP_MEMORY_SCOPE_AGENT);
        __hip_atomic_store(&tbuf[0*(Nn*NWG) + w1], (unsigned)(int)lrintf(pa1*SCALE_) & 0x1FFFFFFu, __ATOMIC_RELAXED, __HIP_MEMORY_SCOPE_AGENT);
        __hip_atomic_store(&tbuf[1*(Nn*NWG) + w0], (1u<<25) | ((unsigned)(int)lrintf(pb0*SCALE_) & 0x1FFFFFFu), __ATOMIC_RELAXED, __HIP_MEMORY_SCOPE_AGENT);
        __hip_atomic_store(&tbuf[1*(Nn*NWG) + w1], (1u<<25) | ((unsigned)(int)lrintf(pb1*SCALE_) & 0x1FFFFFFu), __ATOMIC_RELAXED, __HIP_MEMORY_SCOPE_AGENT);
        __hip_atomic_store(&tbuf[2*(Nn*NWG) + w0], (2u<<25) | ((unsigned)(int)lrintf(pc0*SCALE_) & 0x1FFFFFFu), __ATOMIC_RELAXED, __HIP_MEMORY_SCOPE_AGENT);
        __hip_atomic_store(&tbuf[2*(Nn*NWG) + w1], (2u<<25) | ((unsigned)(int)lrintf(pc1*SCALE_) & 0x1FFFFFFu), __ATOMIC_RELAXED, __HIP_MEMORY_SCOPE_AGENT);
    }
    asm volatile("s_waitcnt vmcnt(0)" ::: "memory");
    __syncthreads();

    // consumer: two register sets, each refilled every 2 steps (depth-2 pipeline)
    unsigned a0=0,a1=0,a2=0,a3=0,a4=0,a5=0,a6=0,a7=0;
    unsigned b0=0,b1=0,b2=0,b3=0,b4=0,b5=0,b6=0,b7=0;
    int pg8 = 0;
    const unsigned* pj = nullptr;
    if (tid < 64) {
        pg8 = (tid >> 3) * 8;
        pj  = tbuf + j0 + (tid & 7);
        const unsigned* p0 = pj;                    // slot 0 (step 0)
        a0 = __hip_atomic_load(&p0[(pg8+0)*512], __ATOMIC_RELAXED, __HIP_MEMORY_SCOPE_AGENT);
        a1 = __hip_atomic_load(&p0[(pg8+1)*512], __ATOMIC_RELAXED, __HIP_MEMORY_SCOPE_AGENT);
        a2 = __hip_atomic_load(&p0[(pg8+2)*512], __ATOMIC_RELAXED, __HIP_MEMORY_SCOPE_AGENT);
        a3 = __hip_atomic_load(&p0[(pg8+3)*512], __ATOMIC_RELAXED, __HIP_MEMORY_SCOPE_AGENT);
        a4 = __hip_atomic_load(&p0[(pg8+4)*512], __ATOMIC_RELAXED, __HIP_MEMORY_SCOPE_AGENT);
        a5 = __hip_atomic_load(&p0[(pg8+5)*512], __ATOMIC_RELAXED, __HIP_MEMORY_SCOPE_AGENT);
        a6 = __hip_atomic_load(&p0[(pg8+6)*512], __ATOMIC_RELAXED, __HIP_MEMORY_SCOPE_AGENT);
        a7 = __hip_atomic_load(&p0[(pg8+7)*512], __ATOMIC_RELAXED, __HIP_MEMORY_SCOPE_AGENT);
        const unsigned* p1 = pj + 1*(Nn*NWG);       // slot 1 (step 1)
        b0 = __hip_atomic_load(&p1[(pg8+0)*512], __ATOMIC_RELAXED, __HIP_MEMORY_SCOPE_AGENT);
        b1 = __hip_atomic_load(&p1[(pg8+1)*512], __ATOMIC_RELAXED, __HIP_MEMORY_SCOPE_AGENT);
        b2 = __hip_atomic_load(&p1[(pg8+2)*512], __ATOMIC_RELAXED, __HIP_MEMORY_SCOPE_AGENT);
        b3 = __hip_atomic_load(&p1[(pg8+3)*512], __ATOMIC_RELAXED, __HIP_MEMORY_SCOPE_AGENT);
        b4 = __hip_atomic_load(&p1[(pg8+4)*512], __ATOMIC_RELAXED, __HIP_MEMORY_SCOPE_AGENT);
        b5 = __hip_atomic_load(&p1[(pg8+5)*512], __ATOMIC_RELAXED, __HIP_MEMORY_SCOPE_AGENT);
        b6 = __hip_atomic_load(&p1[(pg8+6)*512], __ATOMIC_RELAXED, __HIP_MEMORY_SCOPE_AGENT);
        b7 = __hip_atomic_load(&p1[(pg8+7)*512], __ATOMIC_RELAXED, __HIP_MEMORY_SCOPE_AGENT);
    }

    int thc = 0, tbc = 0;

    auto stepf = [&](int t,
                     unsigned& x0, unsigned& x1, unsigned& x2, unsigned& x3,
                     unsigned& x4, unsigned& x5, unsigned& x6, unsigned& x7) -> bool
    {
        // ---- pre-phase ----
        float nM_pre=0.f, nE_pre=0.f, nI_pre=0.f;
        if (tid < NJ) {
            nM_pre = stM + 0.05f*stMv;
            nE_pre = stE + 0.05f*stEv;
            nI_pre = stI + 0.05f*stIv;
            hist[tid][t & 511] = nE_pre;
            if (thc == NH_-1) eim[tid] = nE_pre - nI_pre;
        }
        asm volatile("s_waitcnt lgkmcnt(0)" ::: "memory");
        __builtin_amdgcn_s_barrier();
        __builtin_amdgcn_sched_barrier(0);
        if (abort_s) return true;

        // ---- main phase ----
        if (tid >= 64) {
            if (t <= TSTEPS-4) {                       // publish bulk(t+3), K=3
                const int gt = tid - 64;
                float g0 = 0.f, g1 = 0.f;
                #pragma unroll
                for (int jl = 0; jl < NJ; ++jl) {
                    g0 += wnr0[jl] * histf[jl*512 + ofs0[jl]];
                    g1 += wnr1[jl] * histf[jl*512 + ofs1[jl]];
                    ofs0[jl] = (ofs0[jl] + 1) & 511;
                    ofs1[jl] = (ofs1[jl] + 1) & 511;
                }
                unsigned* bp = tbuf + ((t+3) & (KBUF-1))*(Nn*NWG);
                const unsigned tg3 = (unsigned)((t+3) & 127) << 25;
                __hip_atomic_store(&bp[w*512 + gt],
                                   tg3 | ((unsigned)(int)lrintf(g0*SCALE_) & 0x1FFFFFFu),
                                   __ATOMIC_RELAXED, __HIP_MEMORY_SCOPE_AGENT);
                __hip_atomic_store(&bp[w*512 + gt + 256],
                                   tg3 | ((unsigned)(int)lrintf(g1*SCALE_) & 0x1FFFFFFu),
                                   __ATOMIC_RELAXED, __HIP_MEMORY_SCOPE_AGENT);
            }
            if (thc == NH_-1 && tid < 64 + NEEG) {
                int e = tid - 64;
                float s = 0.f;
                #pragma unroll
                for (int jl = 0; jl < NJ; ++jl) s += lmt_l[e][jl]*eim[jl];
                eeg_l[tbc][e] = s;
            }
        } else {
            float stim=0.f, rE0=0.f, nMv=0.f, nIv=0.f, nz=0.f;
            if (tid < NJ) {
                nz = noise_l[tid][t];
                stim = win0*u_l[2*t] + win1*u_l[2*t+1];
                // fast sigmoids: vmax * rcp(1 + exp(-rr*(x-v0)))
                float rM  = vmax * frcp_(1.0f + __expf(-rr*((stE - stI) - v0p)));
                float s1v = vmax * frcp_(1.0f + __expf(-rr*((kc1*stM)  - v0p)));
                float s3v = vmax * frcp_(1.0f + __expf(-rr*((kc3*stM)  - v0p)));
                float rI  = kc4*s3v;
                rE0 = kg*(dgd_r*stE) + kc2*s1v;
                nMv = stMv + 0.05f*(rA*aa*(500.0f*ftanh_(rM*0.002f)) - 2.0f*aa*stMv - aa*aa*stM);
                nIv = stIv + 0.05f*(rB*ab*(500.0f*ftanh_(rI*0.002f)) - 2.0f*ab*stIv - ab*ab*stI);
            }
            const unsigned tg = (unsigned)(t & 127);
            bool ok = ((x0>>25)==tg) && ((x1>>25)==tg) && ((x2>>25)==tg) && ((x3>>25)==tg)
                   && ((x4>>25)==tg) && ((x5>>25)==tg) && ((x6>>25)==tg) && ((x7>>25)==tg);
            unsigned spins = 0; bool to = false;
            const unsigned* pc_ = pj + (t & (KBUF-1))*(Nn*NWG);
            while (!__all(ok)) {
                if (!ok) {
                    x0 = __hip_atomic_load(&pc_[(pg8+0)*512], __ATOMIC_RELAXED, __HIP_MEMORY_SCOPE_AGENT);
                    x1 = __hip_atomic_load(&pc_[(pg8+1)*512], __ATOMIC_RELAXED, __HIP_MEMORY_SCOPE_AGENT);
                    x2 = __hip_atomic_load(&pc_[(pg8+2)*512], __ATOMIC_RELAXED, __HIP_MEMORY_SCOPE_AGENT);
                    x3 = __hip_atomic_load(&pc_[(pg8+3)*512], __ATOMIC_RELAXED, __HIP_MEMORY_SCOPE_AGENT);
                    x4 = __hip_atomic_load(&pc_[(pg8+4)*512], __ATOMIC_RELAXED, __HIP_MEMORY_SCOPE_AGENT);
                    x5 = __hip_atomic_load(&pc_[(pg8+5)*512], __ATOMIC_RELAXED, __HIP_MEMORY_SCOPE_AGENT);
                    x6 = __hip_atomic_load(&pc_[(pg8+6)*512], __ATOMIC_RELAXED, __HIP_MEMORY_SCOPE_AGENT);
                    x7 = __hip_atomic_load(&pc_[(pg8+7)*512], __ATOMIC_RELAXED, __HIP_MEMORY_SCOPE_AGENT);
                    ok = ((x0>>25)==tg) && ((x1>>25)==tg) && ((x2>>25)==tg) && ((x3>>25)==tg)
                      && ((x4>>25)==tg) && ((x5>>25)==tg) && ((x6>>25)==tg) && ((x7>>25)==tg);
                }
                if ((++spins & 255u) == 0u) {
                    if (__hip_atomic_load(abortf, __ATOMIC_RELAXED, __HIP_MEMORY_SCOPE_AGENT) != 0u ||
                        spins > (1u<<18)) {
                        __hip_atomic_store(abortf, 1u, __ATOMIC_RELAXED, __HIP_MEMORY_SCOPE_AGENT);
                        to = true; break;
                    }
                }
            }
            if (to) {
                if (tid == 0) abort_s = 1u;
            } else {
                int qs = sext25_(x0) + sext25_(x1) + sext25_(x2) + sext25_(x3)
                       + sext25_(x4) + sext25_(x5) + sext25_(x6) + sext25_(x7);
                qs += __shfl_xor(qs, 8);
                qs += __shfl_xor(qs, 16);
                qs += __shfl_xor(qs, 32);
                // refill THIS set for step t+2 (one period of flight before use)
                if (t + 2 < TSTEPS) {
                    const unsigned* pn = pj + ((t+2) & (KBUF-1))*(Nn*NWG);
                    x0 = __hip_atomic_load(&pn[(pg8+0)*512], __ATOMIC_RELAXED, __HIP_MEMORY_SCOPE_AGENT);
                    x1 = __hip_atomic_load(&pn[(pg8+1)*512], __ATOMIC_RELAXED, __HIP_MEMORY_SCOPE_AGENT);
                    x2 = __hip_atomic_load(&pn[(pg8+2)*512], __ATOMIC_RELAXED, __HIP_MEMORY_SCOPE_AGENT);
                    x3 = __hip_atomic_load(&pn[(pg8+3)*512], __ATOMIC_RELAXED, __HIP_MEMORY_SCOPE_AGENT);
                    x4 = __hip_atomic_load(&pn[(pg8+4)*512], __ATOMIC_RELAXED, __HIP_MEMORY_SCOPE_AGENT);
                    x5 = __hip_atomic_load(&pn[(pg8+5)*512], __ATOMIC_RELAXED, __HIP_MEMORY_SCOPE_AGENT);
                    x6 = __hip_atomic_load(&pn[(pg8+6)*512], __ATOMIC_RELAXED, __HIP_MEMORY_SCOPE_AGENT);
                    x7 = __hip_atomic_load(&pn[(pg8+7)*512], __ATOMIC_RELAXED, __HIP_MEMORY_SCOPE_AGENT);
                }
                if (tid < NJ) {
                    float LEd = (float)qs * INVSCALE_;
                    float rE = rE0 + kstd*nz + kg*LEd;
                    float nEv = stEv + 0.05f*(rA*aa*(stim + 500.0f*ftanh_(rE*0.002f)) - 2.0f*aa*stEv - aa*aa*stE);
                    stM = nM_pre; stE = nE_pre; stI = nI_pre;
                    stMv = nMv; stEv = nEv; stIv = nIv;
                }
            }
        }
        return false;
    };

    for (int t = 0; t < TSTEPS; t += 2) {
        if (stepf(t, a0,a1,a2,a3,a4,a5,a6,a7)) break;
        if (thc == NH_-1) { thc = 0; ++tbc; } else ++thc;
        if (stepf(t+1, b0,b1,b2,b3,b4,b5,b6,b7)) break;
        if (thc == NH_-1) { thc = 0; ++tbc; } else ++thc;
    }

    __syncthreads();
    if (abort_s == 0u) {
        const float* el = &eeg_l[0][0];
        for (int idx = tid; idx < NB_*NEEG; idx += NT)
            atomicAdd(&ws[OFF_EEG + idx], el[idx]);
    }
}

__global__ void k_out(const float* __restrict__ ws, const float* __restrict__ theta,
                      float* __restrict__ out)
{
    int idx = blockIdx.x*256 + threadIdx.x;
    if (idx < NB_*NEEG) out[idx] = 0.01f*theta[13]*ws[OFF_EEG + idx] - theta[14];
}

extern "C" void kernel_launch(void* const* d_in, const int* in_sizes, int n_in,
                              void* d_out, int out_size, void* d_ws, size_t ws_size,
                              hipStream_t stream)
{
    const float* input    = (const float*)d_in[0];
    const float* noise_in = (const float*)d_in[1];
    const float* hx       = (const float*)d_in[3];
    const float* hE       = (const float*)d_in[4];
    const float* sc       = (const float*)d_in[5];
    const float* dist     = (const float*)d_in[6];
    const float* w_bb     = (const float*)d_in[7];
    const float* W_in     = (const float*)d_in[8];
    const float* lm       = (const float*)d_in[10];
    const float* theta    = (const float*)d_in[11];
    float* ws  = (float*)d_ws;
    float* out = (float*)d_out;

    hipMemsetAsync(d_ws, 0, (size_t)OFF_ZEND*4, stream);
    hipMemsetAsync((char*)d_ws + (size_t)OFF_TBUF*4, 0xFF,
                   (size_t)TBUF_WORDS*4, stream);              // tags invalid
    k_ws  <<<Nn, 256, 0, stream>>>(w_bb, sc, ws);
    k_main<<<NWG, NT, 0, stream>>>(input, noise_in, hx, hE, dist, W_in, theta,
                                   w_bb, sc, lm, ws);
    k_out <<<(NB_*NEEG + 255)/256, 256, 0, stream>>>(ws, theta, out);
}

// Round 18
// 672.330 us; speedup vs baseline: 1.2249x; 1.1113x over previous
//
#include <hip/hip_runtime.h>
#include <math.h>

#define Nn     512
#define Ll     500
#define TSTEPS 800
#define NWG    64
#define NJ     8      // nodes per workgroup
#define NT     320    // 5 waves: wave0 control, waves 1-4 gather (2 targets/lane)
#define NEEG   64
#define NB_    40
#define NH_    20
#define KBUF   8      // step-indexed ring (power of 2)
#define SCALE_    524288.0f
#define INVSCALE_ (1.0f/524288.0f)

// d_ws layout (float/u32 indices)
#define OFF_SUMSQ  0
#define OFF_ABORT  1
#define OFF_ROWSUM 64                     // f32[512]
#define OFF_EEG    576                    // f32[2560]
#define OFF_ZEND   3200                   // zero [0, OFF_ZEND)
#define OFF_TBUF   3200                   // u32[KBUF*Nn*NWG]
#define TBUF_WORDS (KBUF*Nn*NWG)

__device__ __forceinline__ float relu_(float x) { return fmaxf(x, 0.0f); }
__device__ __forceinline__ int sext25_(unsigned u) { return ((int)(u << 7)) >> 7; }
__device__ __forceinline__ float frcp_(float x) { return __builtin_amdgcn_rcpf(x); }
__device__ __forceinline__ float ftanh_(float x) {
    float e = __expf(2.0f*x);
    return (e - 1.0f) * frcp_(e + 1.0f);
}

__global__ void k_ws(const float* __restrict__ wbb, const float* __restrict__ sc,
                     float* __restrict__ ws)
{
    int i = blockIdx.x, tid = threadIdx.x;
    float rs = 0.f, sq = 0.f;
    for (int j = tid; j < Nn; j += 256) {
        float wij = expf(wbb[i*Nn+j]) * sc[i*Nn+j];
        float wji = expf(wbb[j*Nn+i]) * sc[j*Nn+i];
        float v = log1pf(0.5f*(wij + wji));
        rs += v; sq += v*v;
    }
    #pragma unroll
    for (int off = 32; off > 0; off >>= 1) { rs += __shfl_down(rs, off); sq += __shfl_down(sq, off); }
    __shared__ float srs[4], ssq[4];
    int wv = tid >> 6, ln = tid & 63;
    if (ln == 0) { srs[wv] = rs; ssq[wv] = sq; }
    __syncthreads();
    if (tid == 0) {
        ws[OFF_ROWSUM + i] = srs[0]+srs[1]+srs[2]+srs[3];
        atomicAdd(&ws[OFF_SUMSQ], ssq[0]+ssq[1]+ssq[2]+ssq[3]);
    }
}

__global__ __launch_bounds__(NT) void k_main(
    const float* __restrict__ input, const float* __restrict__ noise_in,
    const float* __restrict__ hx, const float* __restrict__ hE,
    const float* __restrict__ dist, const float* __restrict__ W_in,
    const float* __restrict__ theta, const float* __restrict__ wbb,
    const float* __restrict__ sc, const float* __restrict__ lm,
    float* __restrict__ ws)
{
    __shared__ float hist[NJ][512];          // 16 KB
    __shared__ float wn[NJ][Nn];             // 16 KB
    __shared__ unsigned short dd[NJ][Nn];    //  8 KB (delays clamped to >=3)
    __shared__ float u_l[TSTEPS*2];          // 6.4 KB
    __shared__ float noise_l[NJ][TSTEPS];    // 25.6 KB
    __shared__ float lmt_l[NEEG][NJ];        //  2 KB
    __shared__ float eeg_l[NB_][NEEG];       // 10.2 KB
    __shared__ float colmean[NJ];
    __shared__ float eim[NJ];
    __shared__ unsigned cnt_l;               // control progress: hist[0..cnt-1] valid
    __shared__ unsigned abort_s;

    const int w   = blockIdx.x;
    const int tid = threadIdx.x;
    const int j0  = w*NJ;
    float* histf  = &hist[0][0];

    float th[16];
    #pragma unroll
    for (int k = 0; k < 16; ++k) th[k] = theta[k];
    const float kg   = 0.01f + relu_(th[0]);
    const float kc1  = 0.01f + relu_(th[1]);
    const float kc2  = 0.01f + relu_(th[2]);
    const float kc3  = 0.01f + relu_(th[3]);
    const float kc4  = 0.01f + relu_(th[4]);
    const float kstd = 150.0f + relu_(th[5]);
    const float rA   = relu_(th[6]);
    const float aa   = 1.0f + relu_(th[7]);
    const float rB   = relu_(th[8]);
    const float ab   = 1.0f + relu_(th[9]);
    const float vmax = th[10], v0p = th[11], rr = th[12];
    const float den  = 1.5f + relu_(th[15]);
    const float invnorm = 1.0f / sqrtf(ws[OFF_SUMSQ]);

    if (tid == 0) { abort_s = 0u; cnt_l = 0u; }

    // weights (bitwise == k_ws terms) + delays CLAMPED to >=3
    for (int idx = tid; idx < NJ*Nn; idx += NT) {
        int jl = idx >> 9, i = idx & 511;
        int jg = j0 + jl;
        float wij = expf(wbb[jg*Nn+i]) * sc[jg*Nn+i];
        float wji = expf(wbb[i*Nn+jg]) * sc[i*Nn+jg];
        wn[jl][i] = log1pf(0.5f*(wij + wji)) * invnorm;
        int d = (int)(dist[jg*Nn + i] / den);
        dd[jl][i] = (unsigned short)(d < 3 ? 3 : d);
    }
    // slot s holds E(tau), s = tau mod 512; initial: tau=-1-k -> hE[:,k]
    for (int idx = tid; idx < NJ*512; idx += NT) {
        int jl = idx >> 9, s = idx & 511;
        int k = 511 - s;
        hist[jl][s] = (k < Ll) ? hE[(j0+jl)*Ll + k] : 0.0f;
    }
    for (int idx = tid; idx < TSTEPS*2; idx += NT) {
        int t = idx >> 1, s = idx & 1;
        int tt = (t % NH_)*NB_ + (t / NH_);
        u_l[idx] = input[tt*2 + s];
    }
    for (int idx = tid; idx < NJ*TSTEPS; idx += NT) {
        int jl = idx / TSTEPS, t = idx % TSTEPS;
        int tt = (t % NH_)*NB_ + (t / NH_);
        noise_l[jl][t] = noise_in[(size_t)(j0+jl)*(NH_*NB_*3) + tt*3];
    }
    if (tid < NJ) {
        float s = 0.f;
        for (int e = 0; e < NEEG; ++e) s += lm[e*Nn + j0 + tid];
        colmean[tid] = s * (1.0f/NEEG);
    }
    __syncthreads();
    for (int idx = tid; idx < NEEG*NJ; idx += NT) {
        int e = idx / NJ, jl = idx - e*NJ;
        lmt_l[e][jl] = lm[e*Nn + j0 + jl] - colmean[jl];
    }
    float stM=0,stE=0,stI=0,stMv=0,stEv=0,stIv=0, dgd_r=0, win0=0, win1=0;
    if (tid < NJ) {
        stM  = hx[(j0+tid)*6+0]; stE  = hx[(j0+tid)*6+1]; stI  = hx[(j0+tid)*6+2];
        stMv = hx[(j0+tid)*6+3]; stEv = hx[(j0+tid)*6+4]; stIv = hx[(j0+tid)*6+5];
        dgd_r = -ws[OFF_ROWSUM + j0 + tid] * invnorm;
        win0 = W_in[(j0+tid)*2+0]; win1 = W_in[(j0+tid)*2+1];
    }
    __syncthreads();

    unsigned* abortf = (unsigned*)ws + OFF_ABORT;
    unsigned* tbuf   = (unsigned*)ws + OFF_TBUF;

    // prologue: seed slots 0,1,2 (tags 0,1,2); gather regs + offsets (d>=3)
    float wnr0[NJ], wnr1[NJ];
    int   ofs0[NJ], ofs1[NJ];
    if (tid >= 64) {
        const int gt = tid - 64;                     // 0..255; targets gt, gt+256
        float pa0=0.f, pb0=0.f, pc0=0.f, pa1=0.f, pb1=0.f, pc1=0.f;
        #pragma unroll
        for (int jl = 0; jl < NJ; ++jl) {
            int d0 = (int)dd[jl][gt], d1 = (int)dd[jl][gt+256];
            wnr0[jl] = wn[jl][gt];  wnr1[jl] = wn[jl][gt+256];
            ofs0[jl] = (2 - d0) & 511;               // iter g publishes t=g+3, reads (g+2-d) <= g-1
            ofs1[jl] = (2 - d1) & 511;
            pa0 += wnr0[jl] * hist[jl][(511 - d0) & 511];
            pb0 += wnr0[jl] * hist[jl][(512 - d0) & 511];
            pc0 += wnr0[jl] * hist[jl][(513 - d0) & 511];
            pa1 += wnr1[jl] * hist[jl][(511 - d1) & 511];
            pb1 += wnr1[jl] * hist[jl][(512 - d1) & 511];
            pc1 += wnr1[jl] * hist[jl][(513 - d1) & 511];
        }
        const int w0 = w*512 + gt, w1 = w*512 + gt + 256;
        __hip_atomic_store(&tbuf[0*(Nn*NWG) + w0], (unsigned)(int)lrintf(pa0*SCALE_) & 0x1FFFFFFu, __ATOMIC_RELAXED, __HIP_MEMORY_SCOPE_AGENT);
        __hip_atomic_store(&tbuf[0*(Nn*NWG) + w1], (unsigned)(int)lrintf(pa1*SCALE_) & 0x1FFFFFFu, __ATOMIC_RELAXED, __HIP_MEMORY_SCOPE_AGENT);
        __hip_atomic_store(&tbuf[1*(Nn*NWG) + w0], (1u<<25) | ((unsigned)(int)lrintf(pb0*SCALE_) & 0x1FFFFFFu), __ATOMIC_RELAXED, __HIP_MEMORY_SCOPE_AGENT);
        __hip_atomic_store(&tbuf[1*(Nn*NWG) + w1], (1u<<25) | ((unsigned)(int)lrintf(pb1*SCALE_) & 0x1FFFFFFu), __ATOMIC_RELAXED, __HIP_MEMORY_SCOPE_AGENT);
        __hip_atomic_store(&tbuf[2*(Nn*NWG) + w0], (2u<<25) | ((unsigned)(int)lrintf(pc0*SCALE_) & 0x1FFFFFFu), __ATOMIC_RELAXED, __HIP_MEMORY_SCOPE_AGENT);
        __hip_atomic_store(&tbuf[2*(Nn*NWG) + w1], (2u<<25) | ((unsigned)(int)lrintf(pc1*SCALE_) & 0x1FFFFFFu), __ATOMIC_RELAXED, __HIP_MEMORY_SCOPE_AGENT);
    }
    asm volatile("s_waitcnt vmcnt(0)" ::: "memory");
    __syncthreads();

    if (tid < 64) {
        // ================= CONTROL WAVE (free-running) =================
        unsigned a0=0,a1=0,a2=0,a3=0,a4=0,a5=0,a6=0,a7=0;
        unsigned b0=0,b1=0,b2=0,b3=0,b4=0,b5=0,b6=0,b7=0;
        const int pg8 = (tid >> 3) * 8;
        const unsigned* pj = tbuf + j0 + (tid & 7);
        {
            const unsigned* p0 = pj;
            a0 = __hip_atomic_load(&p0[(pg8+0)*512], __ATOMIC_RELAXED, __HIP_MEMORY_SCOPE_AGENT);
            a1 = __hip_atomic_load(&p0[(pg8+1)*512], __ATOMIC_RELAXED, __HIP_MEMORY_SCOPE_AGENT);
            a2 = __hip_atomic_load(&p0[(pg8+2)*512], __ATOMIC_RELAXED, __HIP_MEMORY_SCOPE_AGENT);
            a3 = __hip_atomic_load(&p0[(pg8+3)*512], __ATOMIC_RELAXED, __HIP_MEMORY_SCOPE_AGENT);
            a4 = __hip_atomic_load(&p0[(pg8+4)*512], __ATOMIC_RELAXED, __HIP_MEMORY_SCOPE_AGENT);
            a5 = __hip_atomic_load(&p0[(pg8+5)*512], __ATOMIC_RELAXED, __HIP_MEMORY_SCOPE_AGENT);
            a6 = __hip_atomic_load(&p0[(pg8+6)*512], __ATOMIC_RELAXED, __HIP_MEMORY_SCOPE_AGENT);
            a7 = __hip_atomic_load(&p0[(pg8+7)*512], __ATOMIC_RELAXED, __HIP_MEMORY_SCOPE_AGENT);
            const unsigned* p1 = pj + 1*(Nn*NWG);
            b0 = __hip_atomic_load(&p1[(pg8+0)*512], __ATOMIC_RELAXED, __HIP_MEMORY_SCOPE_AGENT);
            b1 = __hip_atomic_load(&p1[(pg8+1)*512], __ATOMIC_RELAXED, __HIP_MEMORY_SCOPE_AGENT);
            b2 = __hip_atomic_load(&p1[(pg8+2)*512], __ATOMIC_RELAXED, __HIP_MEMORY_SCOPE_AGENT);
            b3 = __hip_atomic_load(&p1[(pg8+3)*512], __ATOMIC_RELAXED, __HIP_MEMORY_SCOPE_AGENT);
            b4 = __hip_atomic_load(&p1[(pg8+4)*512], __ATOMIC_RELAXED, __HIP_MEMORY_SCOPE_AGENT);
            b5 = __hip_atomic_load(&p1[(pg8+5)*512], __ATOMIC_RELAXED, __HIP_MEMORY_SCOPE_AGENT);
            b6 = __hip_atomic_load(&p1[(pg8+6)*512], __ATOMIC_RELAXED, __HIP_MEMORY_SCOPE_AGENT);
            b7 = __hip_atomic_load(&p1[(pg8+7)*512], __ATOMIC_RELAXED, __HIP_MEMORY_SCOPE_AGENT);
        }
        int thc = 0;
        auto ctrl = [&](int t,
                        unsigned& x0, unsigned& x1, unsigned& x2, unsigned& x3,
                        unsigned& x4, unsigned& x5, unsigned& x6, unsigned& x7) -> bool
        {
            // positions (coupling-independent) -> hist[t] -> cnt = t+1
            float nM_pre=0.f, nE_pre=0.f, nI_pre=0.f;
            if (tid < NJ) {
                nM_pre = stM + 0.05f*stMv;
                nE_pre = stE + 0.05f*stEv;
                nI_pre = stI + 0.05f*stIv;
                hist[tid][t & 511] = nE_pre;
                if (thc == NH_-1) eim[tid] = nE_pre - nI_pre;
            }
            asm volatile("s_waitcnt lgkmcnt(0)" ::: "memory");
            __hip_atomic_store(&cnt_l, (unsigned)(t+1), __ATOMIC_RELAXED, __HIP_MEMORY_SCOPE_WORKGROUP);

            float stim=0.f, rE0=0.f, nMv=0.f, nIv=0.f, nz=0.f;
            if (tid < NJ) {
                nz = noise_l[tid][t];
                stim = win0*u_l[2*t] + win1*u_l[2*t+1];
                float rM  = vmax * frcp_(1.0f + __expf(-rr*((stE - stI) - v0p)));
                float s1v = vmax * frcp_(1.0f + __expf(-rr*((kc1*stM)  - v0p)));
                float s3v = vmax * frcp_(1.0f + __expf(-rr*((kc3*stM)  - v0p)));
                float rI  = kc4*s3v;
                rE0 = kg*(dgd_r*stE) + kc2*s1v;
                nMv = stMv + 0.05f*(rA*aa*(500.0f*ftanh_(rM*0.002f)) - 2.0f*aa*stMv - aa*aa*stM);
                nIv = stIv + 0.05f*(rB*ab*(500.0f*ftanh_(rI*0.002f)) - 2.0f*ab*stIv - ab*ab*stI);
            }
            const unsigned tg = (unsigned)(t & 127);
            bool ok = ((x0>>25)==tg) && ((x1>>25)==tg) && ((x2>>25)==tg) && ((x3>>25)==tg)
                   && ((x4>>25)==tg) && ((x5>>25)==tg) && ((x6>>25)==tg) && ((x7>>25)==tg);
            unsigned spins = 0; bool to = false;
            const unsigned* pc_ = pj + (t & (KBUF-1))*(Nn*NWG);
            while (!__all(ok)) {
                if (!ok) {
                    x0 = __hip_atomic_load(&pc_[(pg8+0)*512], __ATOMIC_RELAXED, __HIP_MEMORY_SCOPE_AGENT);
                    x1 = __hip_atomic_load(&pc_[(pg8+1)*512], __ATOMIC_RELAXED, __HIP_MEMORY_SCOPE_AGENT);
                    x2 = __hip_atomic_load(&pc_[(pg8+2)*512], __ATOMIC_RELAXED, __HIP_MEMORY_SCOPE_AGENT);
                    x3 = __hip_atomic_load(&pc_[(pg8+3)*512], __ATOMIC_RELAXED, __HIP_MEMORY_SCOPE_AGENT);
                    x4 = __hip_atomic_load(&pc_[(pg8+4)*512], __ATOMIC_RELAXED, __HIP_MEMORY_SCOPE_AGENT);
                    x5 = __hip_atomic_load(&pc_[(pg8+5)*512], __ATOMIC_RELAXED, __HIP_MEMORY_SCOPE_AGENT);
                    x6 = __hip_atomic_load(&pc_[(pg8+6)*512], __ATOMIC_RELAXED, __HIP_MEMORY_SCOPE_AGENT);
                    x7 = __hip_atomic_load(&pc_[(pg8+7)*512], __ATOMIC_RELAXED, __HIP_MEMORY_SCOPE_AGENT);
                    ok = ((x0>>25)==tg) && ((x1>>25)==tg) && ((x2>>25)==tg) && ((x3>>25)==tg)
                      && ((x4>>25)==tg) && ((x5>>25)==tg) && ((x6>>25)==tg) && ((x7>>25)==tg);
                }
                if ((++spins & 255u) == 0u) {
                    if (__hip_atomic_load(abortf, __ATOMIC_RELAXED, __HIP_MEMORY_SCOPE_AGENT) != 0u ||
                        spins > (1u<<20)) {
                        __hip_atomic_store(abortf, 1u, __ATOMIC_RELAXED, __HIP_MEMORY_SCOPE_AGENT);
                        to = true; break;
                    }
                }
            }
            if (to) return true;
            int qs = sext25_(x0) + sext25_(x1) + sext25_(x2) + sext25_(x3)
                   + sext25_(x4) + sext25_(x5) + sext25_(x6) + sext25_(x7);
            qs += __shfl_xor(qs, 8);
            qs += __shfl_xor(qs, 16);
            qs += __shfl_xor(qs, 32);
            if (t + 2 < TSTEPS) {           // refill this set for t+2
                const unsigned* pn = pj + ((t+2) & (KBUF-1))*(Nn*NWG);
                x0 = __hip_atomic_load(&pn[(pg8+0)*512], __ATOMIC_RELAXED, __HIP_MEMORY_SCOPE_AGENT);
                x1 = __hip_atomic_load(&pn[(pg8+1)*512], __ATOMIC_RELAXED, __HIP_MEMORY_SCOPE_AGENT);
                x2 = __hip_atomic_load(&pn[(pg8+2)*512], __ATOMIC_RELAXED, __HIP_MEMORY_SCOPE_AGENT);
                x3 = __hip_atomic_load(&pn[(pg8+3)*512], __ATOMIC_RELAXED, __HIP_MEMORY_SCOPE_AGENT);
                x4 = __hip_atomic_load(&pn[(pg8+4)*512], __ATOMIC_RELAXED, __HIP_MEMORY_SCOPE_AGENT);
                x5 = __hip_atomic_load(&pn[(pg8+5)*512], __ATOMIC_RELAXED, __HIP_MEMORY_SCOPE_AGENT);
                x6 = __hip_atomic_load(&pn[(pg8+6)*512], __ATOMIC_RELAXED, __HIP_MEMORY_SCOPE_AGENT);
                x7 = __hip_atomic_load(&pn[(pg8+7)*512], __ATOMIC_RELAXED, __HIP_MEMORY_SCOPE_AGENT);
            }
            if (tid < NJ) {
                float LEd = (float)qs * INVSCALE_;
                float rE = rE0 + kstd*nz + kg*LEd;
                float nEv = stEv + 0.05f*(rA*aa*(stim + 500.0f*ftanh_(rE*0.002f)) - 2.0f*aa*stEv - aa*aa*stE);
                stM = nM_pre; stE = nE_pre; stI = nI_pre;
                stMv = nMv; stEv = nEv; stIv = nIv;
            }
            return false;
        };
        for (int t = 0; t < TSTEPS; t += 2) {
            if (ctrl(t, a0,a1,a2,a3,a4,a5,a6,a7)) break;
            thc = (thc == NH_-1) ? 0 : thc+1;
            if (ctrl(t+1, b0,b1,b2,b3,b4,b5,b6,b7)) break;
            thc = (thc == NH_-1) ? 0 : thc+1;
        }
        if (tid == 0 && __hip_atomic_load(abortf, __ATOMIC_RELAXED, __HIP_MEMORY_SCOPE_AGENT) != 0u)
            abort_s = 1u;
    } else {
        // ================= GATHER WAVES (free-running, cnt-gated) =================
        const int gt = tid - 64;
        int thc = 0, tbc = 0;
        for (int g = 0; g <= TSTEPS-4; ++g) {
            // wait for control to START iter g (hist slots <= g-1 valid)
            unsigned spins = 0; bool to = false;
            while (__hip_atomic_load(&cnt_l, __ATOMIC_RELAXED, __HIP_MEMORY_SCOPE_WORKGROUP) < (unsigned)(g+1)) {
                if ((++spins & 63u) == 0u) {
                    if (__hip_atomic_load(abortf, __ATOMIC_RELAXED, __HIP_MEMORY_SCOPE_AGENT) != 0u ||
                        spins > (1u<<22)) {
                        __hip_atomic_store(abortf, 1u, __ATOMIC_RELAXED, __HIP_MEMORY_SCOPE_AGENT);
                        to = true; break;
                    }
                }
            }
            if (to) break;
            // gather + publish tags(g+3) into slot (g+3)&7
            float g0 = 0.f, g1 = 0.f;
            #pragma unroll
            for (int jl = 0; jl < NJ; ++jl) {
                g0 += wnr0[jl] * histf[jl*512 + ofs0[jl]];
                g1 += wnr1[jl] * histf[jl*512 + ofs1[jl]];
                ofs0[jl] = (ofs0[jl] + 1) & 511;
                ofs1[jl] = (ofs1[jl] + 1) & 511;
            }
            unsigned* bp = tbuf + ((g+3) & (KBUF-1))*(Nn*NWG);
            const unsigned tg3 = (unsigned)((g+3) & 127) << 25;
            __hip_atomic_store(&bp[w*512 + gt],
                               tg3 | ((unsigned)(int)lrintf(g0*SCALE_) & 0x1FFFFFFu),
                               __ATOMIC_RELAXED, __HIP_MEMORY_SCOPE_AGENT);
            __hip_atomic_store(&bp[w*512 + gt + 256],
                               tg3 | ((unsigned)(int)lrintf(g1*SCALE_) & 0x1FFFFFFu),
                               __ATOMIC_RELAXED, __HIP_MEMORY_SCOPE_AGENT);
            // EEG dot at boundaries (eim written by control before cnt bump)
            if (thc == NH_-1 && tid < 64 + NEEG) {
                int e = tid - 64;
                float s = 0.f;
                #pragma unroll
                for (int jl = 0; jl < NJ; ++jl) s += lmt_l[e][jl]*eim[jl];
                eeg_l[tbc][e] = s;
            }
            if (thc == NH_-1) { thc = 0; ++tbc; } else ++thc;
        }
    }

    __syncthreads();
    if (abort_s == 0u && __hip_atomic_load(abortf, __ATOMIC_RELAXED, __HIP_MEMORY_SCOPE_AGENT) == 0u) {
        // remaining EEG boundaries not covered by gather loop (g>796): t=799 (tbc=39)
        if (tid < NEEG) {
            float s = 0.f;
            #pragma unroll
            for (int jl = 0; jl < NJ; ++jl) s += lmt_l[tid][jl]*eim[jl];
            eeg_l[NB_-1][tid] = s;
        }
        __syncthreads();
        const float* el = &eeg_l[0][0];
        for (int idx = tid; idx < NB_*NEEG; idx += NT)
            atomicAdd(&ws[OFF_EEG + idx], el[idx]);
    }
}

__global__ void k_out(const float* __restrict__ ws, const float* __restrict__ theta,
                      float* __restrict__ out)
{
    int idx = blockIdx.x*256 + threadIdx.x;
    if (idx < NB_*NEEG) out[idx] = 0.01f*theta[13]*ws[OFF_EEG + idx] - theta[14];
}

extern "C" void kernel_launch(void* const* d_in, const int* in_sizes, int n_in,
                              void* d_out, int out_size, void* d_ws, size_t ws_size,
                              hipStream_t stream)
{
    const float* input    = (const float*)d_in[0];
    const float* noise_in = (const float*)d_in[1];
    const float* hx       = (const float*)d_in[3];
    const float* hE       = (const float*)d_in[4];
    const float* sc       = (const float*)d_in[5];
    const float* dist     = (const float*)d_in[6];
    const float* w_bb     = (const float*)d_in[7];
    const float* W_in     = (const float*)d_in[8];
    const float* lm       = (const float*)d_in[10];
    const float* theta    = (const float*)d_in[11];
    float* ws  = (float*)d_ws;
    float* out = (float*)d_out;

    hipMemsetAsync(d_ws, 0, (size_t)OFF_ZEND*4, stream);
    hipMemsetAsync((char*)d_ws + (size_t)OFF_TBUF*4, 0xFF,
                   (size_t)TBUF_WORDS*4, stream);              // tags invalid
    k_ws  <<<Nn, 256, 0, stream>>>(w_bb, sc, ws);
    k_main<<<NWG, NT, 0, stream>>>(input, noise_in, hx, hE, dist, W_in, theta,
                                   w_bb, sc, lm, ws);
    k_out <<<(NB_*NEEG + 255)/256, 256, 0, stream>>>(ws, theta, out);
}

// Round 19
// 580.091 us; speedup vs baseline: 1.4197x; 1.1590x over previous
//
#include <hip/hip_runtime.h>
#include <math.h>

#define Nn     512
#define Ll     500
#define TSTEPS 800
#define NWG    64
#define NJ     8      // nodes per workgroup
#define NT     320    // 5 waves: wave0 control, waves 1-4 gather (2 targets/lane)
#define NEEG   64
#define NB_    40
#define NH_    20
#define KBUF   8      // step-indexed ring (power of 2)
#define KAHEAD 5      // publish lead (delays clamped to >= KAHEAD)
#define SCALE_    524288.0f
#define INVSCALE_ (1.0f/524288.0f)

// d_ws layout (float/u32 indices)
#define OFF_SUMSQ  0
#define OFF_ABORT  1
#define OFF_ROWSUM 64                     // f32[512]
#define OFF_EEG    576                    // f32[2560]
#define OFF_ZEND   3200                   // zero [0, OFF_ZEND)
#define OFF_TBUF   3200                   // u32[KBUF*Nn*NWG]
#define TBUF_WORDS (KBUF*Nn*NWG)

__device__ __forceinline__ float relu_(float x) { return fmaxf(x, 0.0f); }
__device__ __forceinline__ int sext25_(unsigned u) { return ((int)(u << 7)) >> 7; }
__device__ __forceinline__ float frcp_(float x) { return __builtin_amdgcn_rcpf(x); }
__device__ __forceinline__ float ftanh_(float x) {
    float e = __expf(2.0f*x);
    return (e - 1.0f) * frcp_(e + 1.0f);
}

__global__ void k_ws(const float* __restrict__ wbb, const float* __restrict__ sc,
                     float* __restrict__ ws)
{
    int i = blockIdx.x, tid = threadIdx.x;
    float rs = 0.f, sq = 0.f;
    for (int j = tid; j < Nn; j += 256) {
        float wij = expf(wbb[i*Nn+j]) * sc[i*Nn+j];
        float wji = expf(wbb[j*Nn+i]) * sc[j*Nn+i];
        float v = log1pf(0.5f*(wij + wji));
        rs += v; sq += v*v;
    }
    #pragma unroll
    for (int off = 32; off > 0; off >>= 1) { rs += __shfl_down(rs, off); sq += __shfl_down(sq, off); }
    __shared__ float srs[4], ssq[4];
    int wv = tid >> 6, ln = tid & 63;
    if (ln == 0) { srs[wv] = rs; ssq[wv] = sq; }
    __syncthreads();
    if (tid == 0) {
        ws[OFF_ROWSUM + i] = srs[0]+srs[1]+srs[2]+srs[3];
        atomicAdd(&ws[OFF_SUMSQ], ssq[0]+ssq[1]+ssq[2]+ssq[3]);
    }
}

__global__ __launch_bounds__(NT) void k_main(
    const float* __restrict__ input, const float* __restrict__ noise_in,
    const float* __restrict__ hx, const float* __restrict__ hE,
    const float* __restrict__ dist, const float* __restrict__ W_in,
    const float* __restrict__ theta, const float* __restrict__ wbb,
    const float* __restrict__ sc, const float* __restrict__ lm,
    float* __restrict__ ws)
{
    __shared__ float hist[NJ][512];          // 16 KB
    __shared__ float wn[NJ][Nn];             // 16 KB
    __shared__ unsigned short dd[NJ][Nn];    //  8 KB (delays clamped to >= KAHEAD)
    __shared__ float u_l[TSTEPS*2];          // 6.4 KB
    __shared__ float noise_l[NJ][TSTEPS];    // 25.6 KB
    __shared__ float lmt_l[NEEG][NJ];        //  2 KB
    __shared__ float eeg_l[NB_][NEEG];       // 10.2 KB
    __shared__ float colmean[NJ];
    __shared__ float eim[NJ];
    __shared__ unsigned cnt_l;               // control progress: hist[0..cnt-1] valid
    __shared__ unsigned abort_s;

    const int w   = blockIdx.x;
    const int tid = threadIdx.x;
    const int j0  = w*NJ;
    float* histf  = &hist[0][0];

    float th[16];
    #pragma unroll
    for (int k = 0; k < 16; ++k) th[k] = theta[k];
    const float kg   = 0.01f + relu_(th[0]);
    const float kc1  = 0.01f + relu_(th[1]);
    const float kc2  = 0.01f + relu_(th[2]);
    const float kc3  = 0.01f + relu_(th[3]);
    const float kc4  = 0.01f + relu_(th[4]);
    const float kstd = 150.0f + relu_(th[5]);
    const float rA   = relu_(th[6]);
    const float aa   = 1.0f + relu_(th[7]);
    const float rB   = relu_(th[8]);
    const float ab   = 1.0f + relu_(th[9]);
    const float vmax = th[10], v0p = th[11], rr = th[12];
    const float den  = 1.5f + relu_(th[15]);
    const float invnorm = 1.0f / sqrtf(ws[OFF_SUMSQ]);

    if (tid == 0) { abort_s = 0u; cnt_l = 0u; }

    // weights (bitwise == k_ws terms) + delays CLAMPED to >= KAHEAD
    for (int idx = tid; idx < NJ*Nn; idx += NT) {
        int jl = idx >> 9, i = idx & 511;
        int jg = j0 + jl;
        float wij = expf(wbb[jg*Nn+i]) * sc[jg*Nn+i];
        float wji = expf(wbb[i*Nn+jg]) * sc[i*Nn+jg];
        wn[jl][i] = log1pf(0.5f*(wij + wji)) * invnorm;
        int d = (int)(dist[jg*Nn + i] / den);
        dd[jl][i] = (unsigned short)(d < KAHEAD ? KAHEAD : d);
    }
    // slot s holds E(tau), s = tau mod 512; initial: tau=-1-k -> hE[:,k]
    for (int idx = tid; idx < NJ*512; idx += NT) {
        int jl = idx >> 9, s = idx & 511;
        int k = 511 - s;
        hist[jl][s] = (k < Ll) ? hE[(j0+jl)*Ll + k] : 0.0f;
    }
    for (int idx = tid; idx < TSTEPS*2; idx += NT) {
        int t = idx >> 1, s = idx & 1;
        int tt = (t % NH_)*NB_ + (t / NH_);
        u_l[idx] = input[tt*2 + s];
    }
    for (int idx = tid; idx < NJ*TSTEPS; idx += NT) {
        int jl = idx / TSTEPS, t = idx % TSTEPS;
        int tt = (t % NH_)*NB_ + (t / NH_);
        noise_l[jl][t] = noise_in[(size_t)(j0+jl)*(NH_*NB_*3) + tt*3];
    }
    if (tid < NJ) {
        float s = 0.f;
        for (int e = 0; e < NEEG; ++e) s += lm[e*Nn + j0 + tid];
        colmean[tid] = s * (1.0f/NEEG);
    }
    __syncthreads();
    for (int idx = tid; idx < NEEG*NJ; idx += NT) {
        int e = idx / NJ, jl = idx - e*NJ;
        lmt_l[e][jl] = lm[e*Nn + j0 + jl] - colmean[jl];
    }
    float stM=0,stE=0,stI=0,stMv=0,stEv=0,stIv=0, dgd_r=0, win0=0, win1=0;
    if (tid < NJ) {
        stM  = hx[(j0+tid)*6+0]; stE  = hx[(j0+tid)*6+1]; stI  = hx[(j0+tid)*6+2];
        stMv = hx[(j0+tid)*6+3]; stEv = hx[(j0+tid)*6+4]; stIv = hx[(j0+tid)*6+5];
        dgd_r = -ws[OFF_ROWSUM + j0 + tid] * invnorm;
        win0 = W_in[(j0+tid)*2+0]; win1 = W_in[(j0+tid)*2+1];
    }
    __syncthreads();

    unsigned* abortf = (unsigned*)ws + OFF_ABORT;
    unsigned* tbuf   = (unsigned*)ws + OFF_TBUF;

    // prologue: seed slots 0..KAHEAD-1 (tags 0..KAHEAD-1); gather regs + offsets
    float wnr0[NJ], wnr1[NJ];
    int   ofs0[NJ], ofs1[NJ];
    if (tid >= 64) {
        const int gt = tid - 64;                     // 0..255; targets gt, gt+256
        float pm0[KAHEAD], pm1[KAHEAD];
        #pragma unroll
        for (int m = 0; m < KAHEAD; ++m) { pm0[m] = 0.f; pm1[m] = 0.f; }
        #pragma unroll
        for (int jl = 0; jl < NJ; ++jl) {
            int d0 = (int)dd[jl][gt], d1 = (int)dd[jl][gt+256];
            wnr0[jl] = wn[jl][gt];  wnr1[jl] = wn[jl][gt+256];
            ofs0[jl] = (KAHEAD-1 - d0) & 511;        // iter g reads slot (g+KAHEAD-1-d)
            ofs1[jl] = (KAHEAD-1 - d1) & 511;
            #pragma unroll
            for (int m = 0; m < KAHEAD; ++m) {       // step m: E(m-1-d)
                pm0[m] += wnr0[jl] * hist[jl][(511 + m - d0) & 511];
                pm1[m] += wnr1[jl] * hist[jl][(511 + m - d1) & 511];
            }
        }
        const int w0 = w*512 + gt, w1 = w*512 + gt + 256;
        #pragma unroll
        for (int m = 0; m < KAHEAD; ++m) {
            const unsigned tgm = (unsigned)m << 25;
            __hip_atomic_store(&tbuf[m*(Nn*NWG) + w0], tgm | ((unsigned)(int)lrintf(pm0[m]*SCALE_) & 0x1FFFFFFu), __ATOMIC_RELAXED, __HIP_MEMORY_SCOPE_AGENT);
            __hip_atomic_store(&tbuf[m*(Nn*NWG) + w1], tgm | ((unsigned)(int)lrintf(pm1[m]*SCALE_) & 0x1FFFFFFu), __ATOMIC_RELAXED, __HIP_MEMORY_SCOPE_AGENT);
        }
    }
    asm volatile("s_waitcnt vmcnt(0)" ::: "memory");
    __syncthreads();

    if (tid < 64) {
        // ================= CONTROL WAVE (free-running) =================
        unsigned a0=0,a1=0,a2=0,a3=0,a4=0,a5=0,a6=0,a7=0;
        unsigned b0=0,b1=0,b2=0,b3=0,b4=0,b5=0,b6=0,b7=0;
        const int pg8 = (tid >> 3) * 8;
        const unsigned* pj = tbuf + j0 + (tid & 7);
        {
            const unsigned* p0 = pj;
            a0 = __hip_atomic_load(&p0[(pg8+0)*512], __ATOMIC_RELAXED, __HIP_MEMORY_SCOPE_AGENT);
            a1 = __hip_atomic_load(&p0[(pg8+1)*512], __ATOMIC_RELAXED, __HIP_MEMORY_SCOPE_AGENT);
            a2 = __hip_atomic_load(&p0[(pg8+2)*512], __ATOMIC_RELAXED, __HIP_MEMORY_SCOPE_AGENT);
            a3 = __hip_atomic_load(&p0[(pg8+3)*512], __ATOMIC_RELAXED, __HIP_MEMORY_SCOPE_AGENT);
            a4 = __hip_atomic_load(&p0[(pg8+4)*512], __ATOMIC_RELAXED, __HIP_MEMORY_SCOPE_AGENT);
            a5 = __hip_atomic_load(&p0[(pg8+5)*512], __ATOMIC_RELAXED, __HIP_MEMORY_SCOPE_AGENT);
            a6 = __hip_atomic_load(&p0[(pg8+6)*512], __ATOMIC_RELAXED, __HIP_MEMORY_SCOPE_AGENT);
            a7 = __hip_atomic_load(&p0[(pg8+7)*512], __ATOMIC_RELAXED, __HIP_MEMORY_SCOPE_AGENT);
            const unsigned* p1 = pj + 1*(Nn*NWG);
            b0 = __hip_atomic_load(&p1[(pg8+0)*512], __ATOMIC_RELAXED, __HIP_MEMORY_SCOPE_AGENT);
            b1 = __hip_atomic_load(&p1[(pg8+1)*512], __ATOMIC_RELAXED, __HIP_MEMORY_SCOPE_AGENT);
            b2 = __hip_atomic_load(&p1[(pg8+2)*512], __ATOMIC_RELAXED, __HIP_MEMORY_SCOPE_AGENT);
            b3 = __hip_atomic_load(&p1[(pg8+3)*512], __ATOMIC_RELAXED, __HIP_MEMORY_SCOPE_AGENT);
            b4 = __hip_atomic_load(&p1[(pg8+4)*512], __ATOMIC_RELAXED, __HIP_MEMORY_SCOPE_AGENT);
            b5 = __hip_atomic_load(&p1[(pg8+5)*512], __ATOMIC_RELAXED, __HIP_MEMORY_SCOPE_AGENT);
            b6 = __hip_atomic_load(&p1[(pg8+6)*512], __ATOMIC_RELAXED, __HIP_MEMORY_SCOPE_AGENT);
            b7 = __hip_atomic_load(&p1[(pg8+7)*512], __ATOMIC_RELAXED, __HIP_MEMORY_SCOPE_AGENT);
        }
        int thc = 0;
        auto ctrl = [&](int t,
                        unsigned& x0, unsigned& x1, unsigned& x2, unsigned& x3,
                        unsigned& x4, unsigned& x5, unsigned& x6, unsigned& x7) -> bool
        {
            float nM_pre=0.f, nE_pre=0.f, nI_pre=0.f;
            if (tid < NJ) {
                nM_pre = stM + 0.05f*stMv;
                nE_pre = stE + 0.05f*stEv;
                nI_pre = stI + 0.05f*stIv;
                hist[tid][t & 511] = nE_pre;
                if (thc == NH_-1) eim[tid] = nE_pre - nI_pre;
            }
            asm volatile("s_waitcnt lgkmcnt(0)" ::: "memory");
            __hip_atomic_store(&cnt_l, (unsigned)(t+1), __ATOMIC_RELAXED, __HIP_MEMORY_SCOPE_WORKGROUP);

            float stim=0.f, rE0=0.f, nMv=0.f, nIv=0.f, nz=0.f;
            if (tid < NJ) {
                nz = noise_l[tid][t];
                stim = win0*u_l[2*t] + win1*u_l[2*t+1];
                float rM  = vmax * frcp_(1.0f + __expf(-rr*((stE - stI) - v0p)));
                float s1v = vmax * frcp_(1.0f + __expf(-rr*((kc1*stM)  - v0p)));
                float s3v = vmax * frcp_(1.0f + __expf(-rr*((kc3*stM)  - v0p)));
                float rI  = kc4*s3v;
                rE0 = kg*(dgd_r*stE) + kc2*s1v;
                nMv = stMv + 0.05f*(rA*aa*(500.0f*ftanh_(rM*0.002f)) - 2.0f*aa*stMv - aa*aa*stM);
                nIv = stIv + 0.05f*(rB*ab*(500.0f*ftanh_(rI*0.002f)) - 2.0f*ab*stIv - ab*ab*stI);
            }
            const unsigned tg = (unsigned)(t & 127);
            bool ok = ((x0>>25)==tg) && ((x1>>25)==tg) && ((x2>>25)==tg) && ((x3>>25)==tg)
                   && ((x4>>25)==tg) && ((x5>>25)==tg) && ((x6>>25)==tg) && ((x7>>25)==tg);
            unsigned spins = 0; bool to = false;
            const unsigned* pc_ = pj + (t & (KBUF-1))*(Nn*NWG);
            while (!__all(ok)) {
                if (!ok) {
                    x0 = __hip_atomic_load(&pc_[(pg8+0)*512], __ATOMIC_RELAXED, __HIP_MEMORY_SCOPE_AGENT);
                    x1 = __hip_atomic_load(&pc_[(pg8+1)*512], __ATOMIC_RELAXED, __HIP_MEMORY_SCOPE_AGENT);
                    x2 = __hip_atomic_load(&pc_[(pg8+2)*512], __ATOMIC_RELAXED, __HIP_MEMORY_SCOPE_AGENT);
                    x3 = __hip_atomic_load(&pc_[(pg8+3)*512], __ATOMIC_RELAXED, __HIP_MEMORY_SCOPE_AGENT);
                    x4 = __hip_atomic_load(&pc_[(pg8+4)*512], __ATOMIC_RELAXED, __HIP_MEMORY_SCOPE_AGENT);
                    x5 = __hip_atomic_load(&pc_[(pg8+5)*512], __ATOMIC_RELAXED, __HIP_MEMORY_SCOPE_AGENT);
                    x6 = __hip_atomic_load(&pc_[(pg8+6)*512], __ATOMIC_RELAXED, __HIP_MEMORY_SCOPE_AGENT);
                    x7 = __hip_atomic_load(&pc_[(pg8+7)*512], __ATOMIC_RELAXED, __HIP_MEMORY_SCOPE_AGENT);
                    ok = ((x0>>25)==tg) && ((x1>>25)==tg) && ((x2>>25)==tg) && ((x3>>25)==tg)
                      && ((x4>>25)==tg) && ((x5>>25)==tg) && ((x6>>25)==tg) && ((x7>>25)==tg);
                }
                if ((++spins & 255u) == 0u) {
                    if (__hip_atomic_load(abortf, __ATOMIC_RELAXED, __HIP_MEMORY_SCOPE_AGENT) != 0u ||
                        spins > (1u<<20)) {
                        __hip_atomic_store(abortf, 1u, __ATOMIC_RELAXED, __HIP_MEMORY_SCOPE_AGENT);
                        to = true; break;
                    }
                }
            }
            if (to) return true;
            int qs = sext25_(x0) + sext25_(x1) + sext25_(x2) + sext25_(x3)
                   + sext25_(x4) + sext25_(x5) + sext25_(x6) + sext25_(x7);
            qs += __shfl_xor(qs, 8);
            qs += __shfl_xor(qs, 16);
            qs += __shfl_xor(qs, 32);
            if (t + 2 < TSTEPS) {           // refill this set for t+2
                const unsigned* pn = pj + ((t+2) & (KBUF-1))*(Nn*NWG);
                x0 = __hip_atomic_load(&pn[(pg8+0)*512], __ATOMIC_RELAXED, __HIP_MEMORY_SCOPE_AGENT);
                x1 = __hip_atomic_load(&pn[(pg8+1)*512], __ATOMIC_RELAXED, __HIP_MEMORY_SCOPE_AGENT);
                x2 = __hip_atomic_load(&pn[(pg8+2)*512], __ATOMIC_RELAXED, __HIP_MEMORY_SCOPE_AGENT);
                x3 = __hip_atomic_load(&pn[(pg8+3)*512], __ATOMIC_RELAXED, __HIP_MEMORY_SCOPE_AGENT);
                x4 = __hip_atomic_load(&pn[(pg8+4)*512], __ATOMIC_RELAXED, __HIP_MEMORY_SCOPE_AGENT);
                x5 = __hip_atomic_load(&pn[(pg8+5)*512], __ATOMIC_RELAXED, __HIP_MEMORY_SCOPE_AGENT);
                x6 = __hip_atomic_load(&pn[(pg8+6)*512], __ATOMIC_RELAXED, __HIP_MEMORY_SCOPE_AGENT);
                x7 = __hip_atomic_load(&pn[(pg8+7)*512], __ATOMIC_RELAXED, __HIP_MEMORY_SCOPE_AGENT);
            }
            if (tid < NJ) {
                float LEd = (float)qs * INVSCALE_;
                float rE = rE0 + kstd*nz + kg*LEd;
                float nEv = stEv + 0.05f*(rA*aa*(stim + 500.0f*ftanh_(rE*0.002f)) - 2.0f*aa*stEv - aa*aa*stE);
                stM = nM_pre; stE = nE_pre; stI = nI_pre;
                stMv = nMv; stEv = nEv; stIv = nIv;
            }
            return false;
        };
        for (int t = 0; t < TSTEPS; t += 2) {
            if (ctrl(t, a0,a1,a2,a3,a4,a5,a6,a7)) break;
            thc = (thc == NH_-1) ? 0 : thc+1;
            if (ctrl(t+1, b0,b1,b2,b3,b4,b5,b6,b7)) break;
            thc = (thc == NH_-1) ? 0 : thc+1;
        }
        if (tid == 0 && __hip_atomic_load(abortf, __ATOMIC_RELAXED, __HIP_MEMORY_SCOPE_AGENT) != 0u)
            abort_s = 1u;
    } else {
        // ================= GATHER WAVES (free-running, cnt-gated) =================
        const int gt = tid - 64;
        int thc = 0, tbc = 0;
        for (int g = 0; g <= TSTEPS-1-KAHEAD; ++g) {
            unsigned spins = 0; bool to = false;
            while (__hip_atomic_load(&cnt_l, __ATOMIC_RELAXED, __HIP_MEMORY_SCOPE_WORKGROUP) < (unsigned)(g+1)) {
                if ((++spins & 63u) == 0u) {
                    if (__hip_atomic_load(abortf, __ATOMIC_RELAXED, __HIP_MEMORY_SCOPE_AGENT) != 0u ||
                        spins > (1u<<22)) {
                        __hip_atomic_store(abortf, 1u, __ATOMIC_RELAXED, __HIP_MEMORY_SCOPE_AGENT);
                        to = true; break;
                    }
                }
            }
            if (to) break;
            // gather + publish tags(g+KAHEAD)
            float g0 = 0.f, g1 = 0.f;
            #pragma unroll
            for (int jl = 0; jl < NJ; ++jl) {
                g0 += wnr0[jl] * histf[jl*512 + ofs0[jl]];
                g1 += wnr1[jl] * histf[jl*512 + ofs1[jl]];
                ofs0[jl] = (ofs0[jl] + 1) & 511;
                ofs1[jl] = (ofs1[jl] + 1) & 511;
            }
            unsigned* bp = tbuf + ((g+KAHEAD) & (KBUF-1))*(Nn*NWG);
            const unsigned tgk = (unsigned)((g+KAHEAD) & 127) << 25;
            __hip_atomic_store(&bp[w*512 + gt],
                               tgk | ((unsigned)(int)lrintf(g0*SCALE_) & 0x1FFFFFFu),
                               __ATOMIC_RELAXED, __HIP_MEMORY_SCOPE_AGENT);
            __hip_atomic_store(&bp[w*512 + gt + 256],
                               tgk | ((unsigned)(int)lrintf(g1*SCALE_) & 0x1FFFFFFu),
                               __ATOMIC_RELAXED, __HIP_MEMORY_SCOPE_AGENT);
            // EEG dot at boundaries (eim written by control before cnt bump)
            if (thc == NH_-1 && tid < 64 + NEEG) {
                int e = tid - 64;
                float s = 0.f;
                #pragma unroll
                for (int jl = 0; jl < NJ; ++jl) s += lmt_l[e][jl]*eim[jl];
                eeg_l[tbc][e] = s;
            }
            if (thc == NH_-1) { thc = 0; ++tbc; } else ++thc;
        }
    }

    __syncthreads();
    if (abort_s == 0u && __hip_atomic_load(abortf, __ATOMIC_RELAXED, __HIP_MEMORY_SCOPE_AGENT) == 0u) {
        // final EEG boundary (t=799, tbc=39) — gather loop ends before it
        if (tid < NEEG) {
            float s = 0.f;
            #pragma unroll
            for (int jl = 0; jl < NJ; ++jl) s += lmt_l[tid][jl]*eim[jl];
            eeg_l[NB_-1][tid] = s;
        }
        __syncthreads();
        const float* el = &eeg_l[0][0];
        for (int idx = tid; idx < NB_*NEEG; idx += NT)
            atomicAdd(&ws[OFF_EEG + idx], el[idx]);
    }
}

__global__ void k_out(const float* __restrict__ ws, const float* __restrict__ theta,
                      float* __restrict__ out)
{
    int idx = blockIdx.x*256 + threadIdx.x;
    if (idx < NB_*NEEG) out[idx] = 0.01f*theta[13]*ws[OFF_EEG + idx] - theta[14];
}

extern "C" void kernel_launch(void* const* d_in, const int* in_sizes, int n_in,
                              void* d_out, int out_size, void* d_ws, size_t ws_size,
                              hipStream_t stream)
{
    const float* input    = (const float*)d_in[0];
    const float* noise_in = (const float*)d_in[1];
    const float* hx       = (const float*)d_in[3];
    const float* hE       = (const float*)d_in[4];
    const float* sc       = (const float*)d_in[5];
    const float* dist     = (const float*)d_in[6];
    const float* w_bb     = (const float*)d_in[7];
    const float* W_in     = (const float*)d_in[8];
    const float* lm       = (const float*)d_in[10];
    const float* theta    = (const float*)d_in[11];
    float* ws  = (float*)d_ws;
    float* out = (float*)d_out;

    hipMemsetAsync(d_ws, 0, (size_t)OFF_ZEND*4, stream);
    hipMemsetAsync((char*)d_ws + (size_t)OFF_TBUF*4, 0xFF,
                   (size_t)TBUF_WORDS*4, stream);              // tags invalid
    k_ws  <<<Nn, 256, 0, stream>>>(w_bb, sc, ws);
    k_main<<<NWG, NT, 0, stream>>>(input, noise_in, hx, hE, dist, W_in, theta,
                                   w_bb, sc, lm, ws);
    k_out <<<(NB_*NEEG + 255)/256, 256, 0, stream>>>(ws, theta, out);
}

// Round 21
// 575.575 us; speedup vs baseline: 1.4308x; 1.0078x over previous
//
#include <hip/hip_runtime.h>
#include <math.h>

#define Nn     512
#define Ll     500
#define TSTEPS 800
#define NWG    64
#define NJ     8      // nodes per workgroup
#define NT     320    // 5 waves: wave0 control, waves 1-4 gather (2 targets/lane)
#define NEEG   64
#define NB_    40
#define NH_    20
#define KBUF   16     // step-indexed ring (power of 2); alias needs step-diff 16 > max 12
#define KAHEAD 6      // publish lead (delays clamped to >= KAHEAD)
#define SCALE_    524288.0f
#define INVSCALE_ (1.0f/524288.0f)

// d_ws layout (float/u32 indices)
#define OFF_SUMSQ  0
#define OFF_ABORT  1
#define OFF_ROWSUM 64                     // f32[512]
#define OFF_EEG    576                    // f32[2560]
#define OFF_ZEND   3200                   // zero [0, OFF_ZEND)
#define OFF_TBUF   3200                   // u32[KBUF*Nn*NWG] = 524288 (~2 MB)
#define TBUF_WORDS (KBUF*Nn*NWG)

__device__ __forceinline__ float relu_(float x) { return fmaxf(x, 0.0f); }
__device__ __forceinline__ int sext25_(unsigned u) { return ((int)(u << 7)) >> 7; }
__device__ __forceinline__ float frcp_(float x) { return __builtin_amdgcn_rcpf(x); }
__device__ __forceinline__ float ftanh_(float x) {
    float e = __expf(2.0f*x);
    return (e - 1.0f) * frcp_(e + 1.0f);
}

__global__ void k_ws(const float* __restrict__ wbb, const float* __restrict__ sc,
                     float* __restrict__ ws)
{
    int i = blockIdx.x, tid = threadIdx.x;
    float rs = 0.f, sq = 0.f;
    for (int j = tid; j < Nn; j += 256) {
        float wij = expf(wbb[i*Nn+j]) * sc[i*Nn+j];
        float wji = expf(wbb[j*Nn+i]) * sc[j*Nn+i];
        float v = log1pf(0.5f*(wij + wji));
        rs += v; sq += v*v;
    }
    #pragma unroll
    for (int off = 32; off > 0; off >>= 1) { rs += __shfl_down(rs, off); sq += __shfl_down(sq, off); }
    __shared__ float srs[4], ssq[4];
    int wv = tid >> 6, ln = tid & 63;
    if (ln == 0) { srs[wv] = rs; ssq[wv] = sq; }
    __syncthreads();
    if (tid == 0) {
        ws[OFF_ROWSUM + i] = srs[0]+srs[1]+srs[2]+srs[3];
        atomicAdd(&ws[OFF_SUMSQ], ssq[0]+ssq[1]+ssq[2]+ssq[3]);
    }
}

__global__ __launch_bounds__(NT) void k_main(
    const float* __restrict__ input, const float* __restrict__ noise_in,
    const float* __restrict__ hx, const float* __restrict__ hE,
    const float* __restrict__ dist, const float* __restrict__ W_in,
    const float* __restrict__ theta, const float* __restrict__ wbb,
    const float* __restrict__ sc, const float* __restrict__ lm,
    float* __restrict__ ws)
{
    __shared__ float hist[NJ][512];          // 16 KB
    __shared__ float wn[NJ][Nn];             // 16 KB
    __shared__ unsigned short dd[NJ][Nn];    //  8 KB (delays clamped to >= KAHEAD)
    __shared__ float u_l[TSTEPS*2];          // 6.4 KB
    __shared__ float noise_l[NJ][TSTEPS];    // 25.6 KB
    __shared__ float lmt_l[NEEG][NJ];        //  2 KB
    __shared__ float eeg_l[NB_][NEEG];       // 10.2 KB
    __shared__ float colmean[NJ];
    __shared__ float eim[NJ];
    __shared__ unsigned cnt_l;               // control progress: hist[0..cnt-1] valid
    __shared__ unsigned abort_s;

    const int w   = blockIdx.x;
    const int tid = threadIdx.x;
    const int j0  = w*NJ;
    float* histf  = &hist[0][0];

    float th[16];
    #pragma unroll
    for (int k = 0; k < 16; ++k) th[k] = theta[k];
    const float kg   = 0.01f + relu_(th[0]);
    const float kc1  = 0.01f + relu_(th[1]);
    const float kc2  = 0.01f + relu_(th[2]);
    const float kc3  = 0.01f + relu_(th[3]);
    const float kc4  = 0.01f + relu_(th[4]);
    const float kstd = 150.0f + relu_(th[5]);
    const float rA   = relu_(th[6]);
    const float aa   = 1.0f + relu_(th[7]);
    const float rB   = relu_(th[8]);
    const float ab   = 1.0f + relu_(th[9]);
    const float vmax = th[10], v0p = th[11], rr = th[12];
    const float den  = 1.5f + relu_(th[15]);
    const float invnorm = 1.0f / sqrtf(ws[OFF_SUMSQ]);

    if (tid == 0) { abort_s = 0u; cnt_l = 0u; }

    // weights (bitwise == k_ws terms) + delays CLAMPED to >= KAHEAD
    for (int idx = tid; idx < NJ*Nn; idx += NT) {
        int jl = idx >> 9, i = idx & 511;
        int jg = j0 + jl;
        float wij = expf(wbb[jg*Nn+i]) * sc[jg*Nn+i];
        float wji = expf(wbb[i*Nn+jg]) * sc[i*Nn+jg];
        wn[jl][i] = log1pf(0.5f*(wij + wji)) * invnorm;
        int d = (int)(dist[jg*Nn + i] / den);
        dd[jl][i] = (unsigned short)(d < KAHEAD ? KAHEAD : d);
    }
    // slot s holds E(tau), s = tau mod 512; initial: tau=-1-k -> hE[:,k]
    for (int idx = tid; idx < NJ*512; idx += NT) {
        int jl = idx >> 9, s = idx & 511;
        int k = 511 - s;
        hist[jl][s] = (k < Ll) ? hE[(j0+jl)*Ll + k] : 0.0f;
    }
    for (int idx = tid; idx < TSTEPS*2; idx += NT) {
        int t = idx >> 1, s = idx & 1;
        int tt = (t % NH_)*NB_ + (t / NH_);
        u_l[idx] = input[tt*2 + s];
    }
    for (int idx = tid; idx < NJ*TSTEPS; idx += NT) {
        int jl = idx / TSTEPS, t = idx % TSTEPS;
        int tt = (t % NH_)*NB_ + (t / NH_);
        noise_l[jl][t] = noise_in[(size_t)(j0+jl)*(NH_*NB_*3) + tt*3];
    }
    if (tid < NJ) {
        float s = 0.f;
        for (int e = 0; e < NEEG; ++e) s += lm[e*Nn + j0 + tid];
        colmean[tid] = s * (1.0f/NEEG);
    }
    __syncthreads();
    for (int idx = tid; idx < NEEG*NJ; idx += NT) {
        int e = idx / NJ, jl = idx - e*NJ;
        lmt_l[e][jl] = lm[e*Nn + j0 + jl] - colmean[jl];
    }
    float stM=0,stE=0,stI=0,stMv=0,stEv=0,stIv=0, dgd_r=0, win0=0, win1=0;
    if (tid < NJ) {
        stM  = hx[(j0+tid)*6+0]; stE  = hx[(j0+tid)*6+1]; stI  = hx[(j0+tid)*6+2];
        stMv = hx[(j0+tid)*6+3]; stEv = hx[(j0+tid)*6+4]; stIv = hx[(j0+tid)*6+5];
        dgd_r = -ws[OFF_ROWSUM + j0 + tid] * invnorm;
        win0 = W_in[(j0+tid)*2+0]; win1 = W_in[(j0+tid)*2+1];
    }
    __syncthreads();

    unsigned* abortf = (unsigned*)ws + OFF_ABORT;
    unsigned* tbuf   = (unsigned*)ws + OFF_TBUF;

    // prologue: seed slots 0..KAHEAD-1 (tags 0..KAHEAD-1); gather regs + offsets
    float wnr0[NJ], wnr1[NJ];
    int   ofs0[NJ], ofs1[NJ];
    if (tid >= 64) {
        const int gt = tid - 64;                     // 0..255; targets gt, gt+256
        float pm0[KAHEAD], pm1[KAHEAD];
        #pragma unroll
        for (int m = 0; m < KAHEAD; ++m) { pm0[m] = 0.f; pm1[m] = 0.f; }
        #pragma unroll
        for (int jl = 0; jl < NJ; ++jl) {
            int d0 = (int)dd[jl][gt], d1 = (int)dd[jl][gt+256];
            wnr0[jl] = wn[jl][gt];  wnr1[jl] = wn[jl][gt+256];
            ofs0[jl] = (KAHEAD-1 - d0) & 511;        // iter g reads slot (g+KAHEAD-1-d)
            ofs1[jl] = (KAHEAD-1 - d1) & 511;
            #pragma unroll
            for (int m = 0; m < KAHEAD; ++m) {       // step m: E(m-1-d)
                pm0[m] += wnr0[jl] * hist[jl][(511 + m - d0) & 511];
                pm1[m] += wnr1[jl] * hist[jl][(511 + m - d1) & 511];
            }
        }
        const int w0 = w*512 + gt, w1 = w*512 + gt + 256;
        #pragma unroll
        for (int m = 0; m < KAHEAD; ++m) {
            const unsigned tgm = (unsigned)m << 25;
            __hip_atomic_store(&tbuf[m*(Nn*NWG) + w0], tgm | ((unsigned)(int)lrintf(pm0[m]*SCALE_) & 0x1FFFFFFu), __ATOMIC_RELAXED, __HIP_MEMORY_SCOPE_AGENT);
            __hip_atomic_store(&tbuf[m*(Nn*NWG) + w1], tgm | ((unsigned)(int)lrintf(pm1[m]*SCALE_) & 0x1FFFFFFu), __ATOMIC_RELAXED, __HIP_MEMORY_SCOPE_AGENT);
        }
    }
    asm volatile("s_waitcnt vmcnt(0)" ::: "memory");
    __syncthreads();

    if (tid < 64) {
        // ============ CONTROL WAVE (free-running, depth-2 consumer pipeline) ============
        unsigned a0=0,a1=0,a2=0,a3=0,a4=0,a5=0,a6=0,a7=0;
        unsigned b0=0,b1=0,b2=0,b3=0,b4=0,b5=0,b6=0,b7=0;
        const int pg8 = (tid >> 3) * 8;
        const unsigned* pj = tbuf + j0 + (tid & 7);
        #define LOAD8(d0_,d1_,d2_,d3_,d4_,d5_,d6_,d7_, base)                                            \
            d0_ = __hip_atomic_load(&(base)[(pg8+0)*512], __ATOMIC_RELAXED, __HIP_MEMORY_SCOPE_AGENT);   \
            d1_ = __hip_atomic_load(&(base)[(pg8+1)*512], __ATOMIC_RELAXED, __HIP_MEMORY_SCOPE_AGENT);   \
            d2_ = __hip_atomic_load(&(base)[(pg8+2)*512], __ATOMIC_RELAXED, __HIP_MEMORY_SCOPE_AGENT);   \
            d3_ = __hip_atomic_load(&(base)[(pg8+3)*512], __ATOMIC_RELAXED, __HIP_MEMORY_SCOPE_AGENT);   \
            d4_ = __hip_atomic_load(&(base)[(pg8+4)*512], __ATOMIC_RELAXED, __HIP_MEMORY_SCOPE_AGENT);   \
            d5_ = __hip_atomic_load(&(base)[(pg8+5)*512], __ATOMIC_RELAXED, __HIP_MEMORY_SCOPE_AGENT);   \
            d6_ = __hip_atomic_load(&(base)[(pg8+6)*512], __ATOMIC_RELAXED, __HIP_MEMORY_SCOPE_AGENT);   \
            d7_ = __hip_atomic_load(&(base)[(pg8+7)*512], __ATOMIC_RELAXED, __HIP_MEMORY_SCOPE_AGENT)
        LOAD8(a0,a1,a2,a3,a4,a5,a6,a7, pj + 0*(Nn*NWG));
        LOAD8(b0,b1,b2,b3,b4,b5,b6,b7, pj + 1*(Nn*NWG));

        int thc = 0;
        auto ctrl = [&](int t,
                        unsigned& x0, unsigned& x1, unsigned& x2, unsigned& x3,
                        unsigned& x4, unsigned& x5, unsigned& x6, unsigned& x7) -> bool
        {
            float nM_pre=0.f, nE_pre=0.f, nI_pre=0.f;
            if (tid < NJ) {
                nM_pre = stM + 0.05f*stMv;
                nE_pre = stE + 0.05f*stEv;
                nI_pre = stI + 0.05f*stIv;
                hist[tid][t & 511] = nE_pre;
                if (thc == NH_-1) eim[tid] = nE_pre - nI_pre;
            }
            asm volatile("s_waitcnt lgkmcnt(0)" ::: "memory");
            __hip_atomic_store(&cnt_l, (unsigned)(t+1), __ATOMIC_RELAXED, __HIP_MEMORY_SCOPE_WORKGROUP);

            float stim=0.f, rE0=0.f, nMv=0.f, nIv=0.f, nz=0.f;
            if (tid < NJ) {
                nz = noise_l[tid][t];
                stim = win0*u_l[2*t] + win1*u_l[2*t+1];
                float rM  = vmax * frcp_(1.0f + __expf(-rr*((stE - stI) - v0p)));
                float s1v = vmax * frcp_(1.0f + __expf(-rr*((kc1*stM)  - v0p)));
                float s3v = vmax * frcp_(1.0f + __expf(-rr*((kc3*stM)  - v0p)));
                float rI  = kc4*s3v;
                rE0 = kg*(dgd_r*stE) + kc2*s1v;
                nMv = stMv + 0.05f*(rA*aa*(500.0f*ftanh_(rM*0.002f)) - 2.0f*aa*stMv - aa*aa*stM);
                nIv = stIv + 0.05f*(rB*ab*(500.0f*ftanh_(rI*0.002f)) - 2.0f*ab*stIv - ab*ab*stI);
            }
            const unsigned tg = (unsigned)(t & 127);
            bool ok = ((x0>>25)==tg) && ((x1>>25)==tg) && ((x2>>25)==tg) && ((x3>>25)==tg)
                   && ((x4>>25)==tg) && ((x5>>25)==tg) && ((x6>>25)==tg) && ((x7>>25)==tg);
            unsigned spins = 0; bool to = false;
            const unsigned* pc_ = pj + (t & (KBUF-1))*(Nn*NWG);
            while (!__all(ok)) {
                if (!ok) {
                    LOAD8(x0,x1,x2,x3,x4,x5,x6,x7, pc_);
                    ok = ((x0>>25)==tg) && ((x1>>25)==tg) && ((x2>>25)==tg) && ((x3>>25)==tg)
                      && ((x4>>25)==tg) && ((x5>>25)==tg) && ((x6>>25)==tg) && ((x7>>25)==tg);
                }
                if ((++spins & 255u) == 0u) {
                    if (__hip_atomic_load(abortf, __ATOMIC_RELAXED, __HIP_MEMORY_SCOPE_AGENT) != 0u ||
                        spins > (1u<<20)) {
                        __hip_atomic_store(abortf, 1u, __ATOMIC_RELAXED, __HIP_MEMORY_SCOPE_AGENT);
                        to = true; break;
                    }
                }
            }
            if (to) return true;
            int qs = sext25_(x0) + sext25_(x1) + sext25_(x2) + sext25_(x3)
                   + sext25_(x4) + sext25_(x5) + sext25_(x6) + sext25_(x7);
            qs += __shfl_xor(qs, 8);
            qs += __shfl_xor(qs, 16);
            qs += __shfl_xor(qs, 32);
            if (t + 2 < TSTEPS) {           // refill this set for t+2
                const unsigned* pn = pj + ((t+2) & (KBUF-1))*(Nn*NWG);
                LOAD8(x0,x1,x2,x3,x4,x5,x6,x7, pn);
            }
            if (tid < NJ) {
                float LEd = (float)qs * INVSCALE_;
                float rE = rE0 + kstd*nz + kg*LEd;
                float nEv = stEv + 0.05f*(rA*aa*(stim + 500.0f*ftanh_(rE*0.002f)) - 2.0f*aa*stEv - aa*aa*stE);
                stM = nM_pre; stE = nE_pre; stI = nI_pre;
                stMv = nMv; stEv = nEv; stIv = nIv;
            }
            return false;
        };
        for (int t = 0; t < TSTEPS; t += 2) {
            if (ctrl(t, a0,a1,a2,a3,a4,a5,a6,a7)) break;
            thc = (thc == NH_-1) ? 0 : thc+1;
            if (ctrl(t+1, b0,b1,b2,b3,b4,b5,b6,b7)) break;
            thc = (thc == NH_-1) ? 0 : thc+1;
        }
        #undef LOAD8
        if (tid == 0 && __hip_atomic_load(abortf, __ATOMIC_RELAXED, __HIP_MEMORY_SCOPE_AGENT) != 0u)
            abort_s = 1u;
    } else {
        // ================= GATHER WAVES (free-running, cnt-gated) =================
        const int gt = tid - 64;
        int thc = 0, tbc = 0;
        for (int g = 0; g <= TSTEPS-1-KAHEAD; ++g) {
            unsigned spins = 0; bool to = false;
            while (__hip_atomic_load(&cnt_l, __ATOMIC_RELAXED, __HIP_MEMORY_SCOPE_WORKGROUP) < (unsigned)(g+1)) {
                if ((++spins & 63u) == 0u) {
                    if (__hip_atomic_load(abortf, __ATOMIC_RELAXED, __HIP_MEMORY_SCOPE_AGENT) != 0u ||
                        spins > (1u<<22)) {
                        __hip_atomic_store(abortf, 1u, __ATOMIC_RELAXED, __HIP_MEMORY_SCOPE_AGENT);
                        to = true; break;
                    }
                }
            }
            if (to) break;
            // gather + publish tags(g+KAHEAD)
            float g0 = 0.f, g1 = 0.f;
            #pragma unroll
            for (int jl = 0; jl < NJ; ++jl) {
                g0 += wnr0[jl] * histf[jl*512 + ofs0[jl]];
                g1 += wnr1[jl] * histf[jl*512 + ofs1[jl]];
                ofs0[jl] = (ofs0[jl] + 1) & 511;
                ofs1[jl] = (ofs1[jl] + 1) & 511;
            }
            unsigned* bp = tbuf + ((g+KAHEAD) & (KBUF-1))*(Nn*NWG);
            const unsigned tgk = (unsigned)((g+KAHEAD) & 127) << 25;
            __hip_atomic_store(&bp[w*512 + gt],
                               tgk | ((unsigned)(int)lrintf(g0*SCALE_) & 0x1FFFFFFu),
                               __ATOMIC_RELAXED, __HIP_MEMORY_SCOPE_AGENT);
            __hip_atomic_store(&bp[w*512 + gt + 256],
                               tgk | ((unsigned)(int)lrintf(g1*SCALE_) & 0x1FFFFFFu),
                               __ATOMIC_RELAXED, __HIP_MEMORY_SCOPE_AGENT);
            // EEG dot at boundaries (eim written by control before cnt bump)
            if (thc == NH_-1 && tid < 64 + NEEG) {
                int e = tid - 64;
                float s = 0.f;
                #pragma unroll
                for (int jl = 0; jl < NJ; ++jl) s += lmt_l[e][jl]*eim[jl];
                eeg_l[tbc][e] = s;
            }
            if (thc == NH_-1) { thc = 0; ++tbc; } else ++thc;
        }
    }

    __syncthreads();
    if (abort_s == 0u && __hip_atomic_load(abortf, __ATOMIC_RELAXED, __HIP_MEMORY_SCOPE_AGENT) == 0u) {
        // final EEG boundary (t=799, tbc=39) — gather loop ends before it
        if (tid < NEEG) {
            float s = 0.f;
            #pragma unroll
            for (int jl = 0; jl < NJ; ++jl) s += lmt_l[tid][jl]*eim[jl];
            eeg_l[NB_-1][tid] = s;
        }
        __syncthreads();
        const float* el = &eeg_l[0][0];
        for (int idx = tid; idx < NB_*NEEG; idx += NT)
            atomicAdd(&ws[OFF_EEG + idx], el[idx]);
    }
}

__global__ void k_out(const float* __restrict__ ws, const float* __restrict__ theta,
                      float* __restrict__ out)
{
    int idx = blockIdx.x*256 + threadIdx.x;
    if (idx < NB_*NEEG) out[idx] = 0.01f*theta[13]*ws[OFF_EEG + idx] - theta[14];
}

extern "C" void kernel_launch(void* const* d_in, const int* in_sizes, int n_in,
                              void* d_out, int out_size, void* d_ws, size_t ws_size,
                              hipStream_t stream)
{
    const float* input    = (const float*)d_in[0];
    const float* noise_in = (const float*)d_in[1];
    const float* hx       = (const float*)d_in[3];
    const float* hE       = (const float*)d_in[4];
    const float* sc       = (const float*)d_in[5];
    const float* dist     = (const float*)d_in[6];
    const float* w_bb     = (const float*)d_in[7];
    const float* W_in     = (const float*)d_in[8];
    const float* lm       = (const float*)d_in[10];
    const float* theta    = (const float*)d_in[11];
    float* ws  = (float*)d_ws;
    float* out = (float*)d_out;

    hipMemsetAsync(d_ws, 0, (size_t)OFF_ZEND*4, stream);
    hipMemsetAsync((char*)d_ws + (size_t)OFF_TBUF*4, 0xFF,
                   (size_t)TBUF_WORDS*4, stream);              // tags invalid
    k_ws  <<<Nn, 256, 0, stream>>>(w_bb, sc, ws);
    k_main<<<NWG, NT, 0, stream>>>(input, noise_in, hx, hE, dist, W_in, theta,
                                   w_bb, sc, lm, ws);
    k_out <<<(NB_*NEEG + 255)/256, 256, 0, stream>>>(ws, theta, out);
}